// Round 9
// baseline (7005.421 us; speedup 1.0000x reference)
//
#include <hip/hip_runtime.h>

// ============================================================================
// 2-layer LSTM (H=1024, B=128, T=256, future=64), persistent cooperative
// kernel, 256 WGs x 512 thr, 1 WG/CU, weights in LDS (MFMA B-frag order).
// R9: pipeline restructure on top of R8's coherence scheme.
//  1) E1(t+1) hoisted into step t (TF): both arrivals land at step end, so
//     the next rendezvous finds counters complete (exposed sync ~= fence+flag).
//  2) h2(t-1) fully prefetched into registers (f16x8 h2r[32], static unroll)
//     right after the flag; h1 k-loop (G1/G2a) streams behind it; G2b runs
//     register-only. ~2x deeper VMEM queue for the latency-bound stream.
//  3) tile3/accO removed: out(t) = partial-dot + f32 atomic-add reduce for
//     ALL steps (proven AR mechanism); writer block (t-1)&255 stores outp
//     after the next rendezvous; epilogue covers the final column.
// ============================================================================

typedef _Float16 f16;
typedef _Float16 f16x8 __attribute__((ext_vector_type(8)));
typedef _Float16 f16x4 __attribute__((ext_vector_type(4)));
typedef float    f32x4 __attribute__((ext_vector_type(4)));
typedef int      i32x4 __attribute__((ext_vector_type(4)));
typedef unsigned int   u32;
typedef unsigned short u16;

#define NB   256
#define WGS  512
#define HS   1024
#define BS   128
#define TS   256
#define TTS  320
#define KST  32      // 1024 / 32
#define PSTR 131072  // f16 per plane: 256*128*4 (H1 and H2)
#define NT   3       // weight tiles: G1(Whh1), G2a(Wih2), G2b(Whh2)

// workspace byte offsets
#define OFF_H1    0u         // f16 [2][256][128][4]        524288 B
#define OFF_H2    524288u    // f16 [2][256][128][4]        524288 B
#define OFF_CNT1  1048576u   // int [64 slots x 1024-int]   262144 B
#define OFF_CNT2  1310720u   // int [64 slots x 1024-int]   262144 B
#define OFF_FLAG  1572864u   // int [8 xcd x 2048-int]       65536 B
#define OFF_XREG  1638400u   // int [8 xcd x 16]               512 B
#define OFF_ACC   1638912u   // float [320][128]            163840 B
#define WS_END    1802752u

#define NSLOT       64
#define SLOT_TGT    4        // 256 blocks / 64 slots
#define SLOT_STRIDE 1024     // ints: 4KB between slots

// LDS byte offsets
#define LDS_G1    98304      // float[128][16]
#define LDS_G2    106496     // float[128][16]
#define LDS_XF    114688     // float[128]
#define LDS_PRM   115200     // wih1[16], b1[16], b2[16], blin
#define LDS_MISC  115456     // int[2]: xcd, leader
#define LDS_SH1   115584     // f16[512] stage h1 [row][4]
#define LDS_SH2   116608     // f16[512] stage h2 [row][4]
#define LDS_TOTAL 117760

__device__ __forceinline__ float sigm(float x){ return 1.0f/(1.0f + __expf(-x)); }

__device__ __forceinline__ void wt_store(u32* p, u32 v) {
  __hip_atomic_store(p, v, __ATOMIC_RELAXED, __HIP_MEMORY_SCOPE_AGENT);
}

// full-line write-through 16B store (to coherence point)
__device__ __forceinline__ void st16_wt(f16* addr, f16x8 v) {
  i32x4 d = __builtin_bit_cast(i32x4, v);
  asm volatile("global_store_dwordx4 %0, %1, off sc0 sc1"
               :: "v"(addr), "v"(d) : "memory");
}

// per-lane slot poll (call from wv7: lane l polls slot l)
__device__ __forceinline__ void poll_slots(const int* cnt, int t) {
  const int* p = cnt + (threadIdx.x & 63) * SLOT_STRIDE + t;
  while (__hip_atomic_load(p, __ATOMIC_RELAXED, __HIP_MEMORY_SCOPE_AGENT) < SLOT_TGT)
    __builtin_amdgcn_s_sleep(1);
}

__global__ void init_ws_kernel(char* ws){
  // zero cnt1 + cnt2 + flags + xreg + accs (contiguous)
  const size_t n = (WS_END - OFF_CNT1) / 16u;
  float4* r = (float4*)(ws + OFF_CNT1);
  float4 z = make_float4(0.f, 0.f, 0.f, 0.f);
  size_t stride = (size_t)gridDim.x * blockDim.x;
  for (size_t i = blockIdx.x*(size_t)blockDim.x + threadIdx.x; i < n; i += stride) r[i] = z;
  __builtin_amdgcn_fence(__ATOMIC_RELEASE, "agent");
}

__global__ void __launch_bounds__(WGS, 2)
lstm_coop(const float* __restrict__ xg,
          const float* __restrict__ Wih1, const float* __restrict__ Whh1,
          const float* __restrict__ bih1, const float* __restrict__ bhh1,
          const float* __restrict__ Wih2, const float* __restrict__ Whh2,
          const float* __restrict__ bih2, const float* __restrict__ bhh2,
          const float* __restrict__ Wlin, const float* __restrict__ blin,
          float* __restrict__ outp, char* __restrict__ ws)
{
  extern __shared__ char smem[];
  f16*   Wlds = (f16*)smem;                    // [(tile*32+k0)*64+lane]*8 f16
  float* g1s  = (float*)(smem + LDS_G1);
  float* g2s  = (float*)(smem + LDS_G2);
  float* xfd  = (float*)(smem + LDS_XF);
  float* prm  = (float*)(smem + LDS_PRM);
  int*   miscl= (int*)(smem + LDS_MISC);
  f16*   sh1  = (f16*)(smem + LDS_SH1);
  f16*   sh2  = (f16*)(smem + LDS_SH2);

  f16* H1  = (f16*)(ws + OFF_H1);
  f16* H2  = (f16*)(ws + OFF_H2);
  int* cnt1 = (int*)(ws + OFF_CNT1);
  int* cnt2 = (int*)(ws + OFF_CNT2);
  int* flags= (int*)(ws + OFF_FLAG);
  float* accs = (float*)(ws + OFF_ACC);

  const int tid = threadIdx.x;
  const int blk = blockIdx.x;

  // ---- XCD self-id + leader election (rank0 of each XCC_ID group) ----
  int xcd_raw;
  asm("s_getreg_b32 %0, hwreg(HW_REG_XCC_ID)" : "=s"(xcd_raw));
  if (tid == 0) {
    int x = xcd_raw & 7;
    int rank = __hip_atomic_fetch_add((int*)(ws + OFF_XREG) + x*16, 1,
                                      __ATOMIC_RELAXED, __HIP_MEMORY_SCOPE_AGENT);
    miscl[0] = x;
    miscl[1] = (rank == 0) ? 1 : 0;
  }

  // ---- prologue: pack weights into LDS in MFMA B-frag order (3 tiles) ----
  for (int item = tid; item < NT*KST*64; item += WGS) {
    int tile = item >> 11;
    int rem  = item & 2047;
    int k0   = rem >> 6;
    int lane = rem & 63;
    int n    = lane & 15;
    int kbase = k0*32 + (lane>>4)*8;
    const float* Wsrc = (tile==0) ? Whh1 : (tile==1) ? Wih2 : Whh2;
    const float* p = Wsrc + (size_t)((n>>2)*1024 + blk*4 + (n&3))*HS + kbase;
    f16x8 pk;
    #pragma unroll
    for (int j=0;j<8;j++) pk[j] = (f16)p[j];
    *(f16x8*)(Wlds + (size_t)item*8) = pk;
  }
  if (tid < 16) {
    int row = (tid>>2)*1024 + blk*4 + (tid&3);
    prm[tid]      = Wih1[row];
    prm[16 + tid] = bih1[row] + bhh1[row];
    prm[32 + tid] = bih2[row] + bhh2[row];
  }
  if (tid == 16) prm[48] = blin[0];

  const int erow = tid >> 2;        // elementwise: batch row
  const int eu   = tid & 3;         // unit within CU
  const float wlin_c = Wlin[blk*4 + eu];
  float c1 = 0.f, c2 = 0.f;
  __syncthreads();

  const int  myxcd  = miscl[0];
  const bool leader = miscl[1] != 0;
  int* flag = flags + myxcd * 2048;         // monotone t+1

  // MFMA identity
  const int wv    = tid >> 6;
  const int lane  = tid & 63;
  const int n15   = lane & 15;
  const int mrow  = wv*16 + n15;          // A-frag row (batch)
  const int kc    = (lane>>4)*8;          // A/B-frag k sub-offset
  const int rbase = wv*16 + (lane>>4)*4;  // C/D row base
  const f16x8* WB = (const f16x8*)Wlds;
  const int abase = mrow*4 + (kc>>2)*512; // frag base (f16), H1 and H2

  // ---- prologue E1(0): h1(0) from x(0) only; store plane 0; arrive ----
  {
    float xv = xg[erow*TS + 0];
    float gi = xv*prm[0*4+eu] + prm[16 + 0*4+eu];
    float gg = xv*prm[2*4+eu] + prm[16 + 2*4+eu];
    float go = xv*prm[3*4+eu] + prm[16 + 3*4+eu];
    c1 = sigm(gi)*tanhf(gg);
    float h1v = sigm(go)*tanhf(c1);
    sh1[tid] = (f16)h1v;
  }
  __syncthreads();
  if (wv == 0) {
    st16_wt(H1 + (size_t)0*PSTR + blk*512 + lane*8, *(const f16x8*)(sh1 + lane*8));
    asm volatile("s_waitcnt vmcnt(0)" ::: "memory");
    if (lane == 0)
      __hip_atomic_fetch_add(cnt1 + (blk & (NSLOT-1))*SLOT_STRIDE + 0, 1,
                             __ATOMIC_RELAXED, __HIP_MEMORY_SCOPE_AGENT);
  }

  for (int t = 0; t < TTS; ++t) {
    const int p1 = t & 1;          // h1(t)/h2(t) plane (this step)
    const int p2 = (t + 1) & 1;    // h2(t-1) plane (read) == h1(t+1) plane

    // ---- [AR pre-phase] (t>=TS): E1(t) needs global out(t-1) ----
    if (t >= TS) {
      if (wv == 7) poll_slots(cnt2, t);
      __syncthreads();
      if (tid < BS)
        xfd[tid] = __hip_atomic_load(accs + (size_t)(t-1)*BS + tid,
                                     __ATOMIC_RELAXED, __HIP_MEMORY_SCOPE_AGENT) + prm[48];
      __syncthreads();
      {
        float xv = xfd[erow];
        float gi = g1s[erow*16 + 0*4+eu] + xv*prm[0*4+eu];
        float gf = g1s[erow*16 + 1*4+eu] + xv*prm[1*4+eu];
        float gg = g1s[erow*16 + 2*4+eu] + xv*prm[2*4+eu];
        float go = g1s[erow*16 + 3*4+eu] + xv*prm[3*4+eu];
        c1 = sigm(gf)*c1 + sigm(gi)*tanhf(gg);
        float h1v = sigm(go)*tanhf(c1);
        sh1[tid] = (f16)h1v;
      }
      __syncthreads();
      if (wv == 0) {
        st16_wt(H1 + (size_t)p1*PSTR + blk*512 + lane*8, *(const f16x8*)(sh1 + lane*8));
        asm volatile("s_waitcnt vmcnt(0)" ::: "memory");
        if (lane == 0)
          __hip_atomic_fetch_add(cnt1 + (blk & (NSLOT-1))*SLOT_STRIDE + t, 1,
                                 __ATOMIC_RELAXED, __HIP_MEMORY_SCOPE_AGENT);
      }
    }

    // ---- [rendezvous] leader: poll both counters -> fence -> flag ----
    if (wv == 7) {
      if (leader) {
        if (t >= 1) poll_slots(cnt2, t);
        poll_slots(cnt1, t);
        __builtin_amdgcn_fence(__ATOMIC_ACQUIRE, "agent");   // one L1+L2 inv
        asm volatile("s_waitcnt vmcnt(0)" ::: "memory");
        if (lane == 0)
          __hip_atomic_store(flag, t + 1, __ATOMIC_RELAXED, __HIP_MEMORY_SCOPE_AGENT);
      } else {
        if (lane == 0) {
          while (__hip_atomic_load(flag, __ATOMIC_RELAXED, __HIP_MEMORY_SCOPE_AGENT) < t + 1)
            __builtin_amdgcn_s_sleep(1);
        }
      }
    }
    __syncthreads();

    // ---- [outp writer] col t-1 (sums final since cnt2[t]) ----
    if (t >= 1 && blk == ((t-1) & 255) && tid < BS) {
      float v = __hip_atomic_load(accs + (size_t)(t-1)*BS + tid,
                                  __ATOMIC_RELAXED, __HIP_MEMORY_SCOPE_AGENT) + prm[48];
      wt_store((u32*)&outp[tid*TTS + (t-1)], __builtin_bit_cast(u32, v));
    }

    // hoist next-step x load (TF)
    float xv_next = 0.0f;
    if (t + 1 <= TS-1) xv_next = xg[erow*TS + (t+1)];

    // ---- [h2 prefetch] full register prefetch (static unroll -> regs) ----
    f16x8 h2r[KST];
    const f16* A2 = H2 + (size_t)p2*PSTR + abase;
    if (t >= 1) {
      #pragma unroll
      for (int k0 = 0; k0 < KST; ++k0) {
        f16x4 lo = *(const f16x4*)(A2 + k0*4096);
        f16x4 hi = *(const f16x4*)(A2 + k0*4096 + 512);
        h2r[k0] = __builtin_shufflevector(lo, hi, 0,1,2,3,4,5,6,7);
      }
    }

    // ---- [h1 stream] G1 + G2a ----
    const f16* A1 = H1 + (size_t)p1*PSTR + abase;
    f32x4 acc1  = {0.f,0.f,0.f,0.f};
    f32x4 acc2a = {0.f,0.f,0.f,0.f};
    f32x4 acc2b = {0.f,0.f,0.f,0.f};
    #pragma unroll 8
    for (int k0 = 0; k0 < KST; ++k0) {
      f16x4 a1l = *(const f16x4*)(A1 + k0*4096);
      f16x4 a1h = *(const f16x4*)(A1 + k0*4096 + 512);
      f16x8 a1  = __builtin_shufflevector(a1l, a1h, 0,1,2,3,4,5,6,7);
      f16x8 b0 = WB[(0*KST + k0)*64 + lane];
      f16x8 b1 = WB[(1*KST + k0)*64 + lane];
      acc1  = __builtin_amdgcn_mfma_f32_16x16x32_f16(a1, b0, acc1,  0,0,0);
      acc2a = __builtin_amdgcn_mfma_f32_16x16x32_f16(a1, b1, acc2a, 0,0,0);
    }
    // ---- [G2b] register-only (prefetched h2) ----
    if (t >= 1) {
      #pragma unroll
      for (int k0 = 0; k0 < KST; ++k0) {
        f16x8 b2 = WB[(2*KST + k0)*64 + lane];
        acc2b = __builtin_amdgcn_mfma_f32_16x16x32_f16(h2r[k0], b2, acc2b, 0,0,0);
      }
    }
    #pragma unroll
    for (int r = 0; r < 4; ++r) {
      int grow = rbase + r;
      g1s[grow*16 + n15] = acc1[r]  + prm[16 + n15];
      g2s[grow*16 + n15] = acc2a[r] + acc2b[r] + prm[32 + n15];
    }
    __syncthreads();

    // ---- [E2(t)] c2, h2; stage; out(t) partial dot + atomic reduce ----
    {
      float gi = g2s[erow*16 + 0*4+eu];
      float gf = g2s[erow*16 + 1*4+eu];
      float gg = g2s[erow*16 + 2*4+eu];
      float go = g2s[erow*16 + 3*4+eu];
      c2 = sigm(gf)*c2 + sigm(gi)*tanhf(gg);
      float h2v = sigm(go)*tanhf(c2);
      sh2[tid] = (f16)h2v;
      float p = h2v * wlin_c;
      p += __shfl_xor(p, 1);
      p += __shfl_xor(p, 2);
      if (eu == 0)
        __hip_atomic_fetch_add(accs + (size_t)t*BS + erow, p,
                               __ATOMIC_RELAXED, __HIP_MEMORY_SCOPE_AGENT);
    }

    // ---- [E1(t+1) hoist] (TF only; AR handled by next step's pre-phase) ----
    if (t + 1 <= TS-1) {
      float xv = xv_next;
      float gi = g1s[erow*16 + 0*4+eu] + xv*prm[0*4+eu];
      float gf = g1s[erow*16 + 1*4+eu] + xv*prm[1*4+eu];
      float gg = g1s[erow*16 + 2*4+eu] + xv*prm[2*4+eu];
      float go = g1s[erow*16 + 3*4+eu] + xv*prm[3*4+eu];
      c1 = sigm(gf)*c1 + sigm(gi)*tanhf(gg);
      float h1v = sigm(go)*tanhf(c1);
      sh1[tid] = (f16)h1v;
    }

    // drain all waves' atomic adds (and stores) before arrivals
    asm volatile("s_waitcnt vmcnt(0)" ::: "memory");
    __syncthreads();

    // ---- [stores + arrivals] last acts of the step ----
    if (wv == 0 && t + 1 <= TS-1) {   // h1(t+1), plane p2
      st16_wt(H1 + (size_t)p2*PSTR + blk*512 + lane*8, *(const f16x8*)(sh1 + lane*8));
      asm volatile("s_waitcnt vmcnt(0)" ::: "memory");
      if (lane == 0)
        __hip_atomic_fetch_add(cnt1 + (blk & (NSLOT-1))*SLOT_STRIDE + (t+1), 1,
                               __ATOMIC_RELAXED, __HIP_MEMORY_SCOPE_AGENT);
    }
    if (wv == 1) {                    // h2(t), plane p1
      st16_wt(H2 + (size_t)p1*PSTR + blk*512 + lane*8, *(const f16x8*)(sh2 + lane*8));
      asm volatile("s_waitcnt vmcnt(0)" ::: "memory");
      if (lane == 0)
        __hip_atomic_fetch_add(cnt2 + (blk & (NSLOT-1))*SLOT_STRIDE + (t+1), 1,
                               __ATOMIC_RELAXED, __HIP_MEMORY_SCOPE_AGENT);
    }
  }

  // ---- epilogue: outp col TTS-1 (writer block 63 = (TTS-1)&255) ----
  if (blk == 63) {
    if (wv == 7) poll_slots(cnt2, TTS);
    __syncthreads();
    if (tid < BS) {
      float v = __hip_atomic_load(accs + (size_t)(TTS-1)*BS + tid,
                                  __ATOMIC_RELAXED, __HIP_MEMORY_SCOPE_AGENT) + prm[48];
      wt_store((u32*)&outp[tid*TTS + (TTS-1)], __builtin_bit_cast(u32, v));
    }
  }
}

extern "C" void kernel_launch(void* const* d_in, const int* in_sizes, int n_in,
                              void* d_out, int out_size, void* d_ws, size_t ws_size,
                              hipStream_t stream) {
  const float* xg   = (const float*)d_in[0];
  const float* Wih1 = (const float*)d_in[1];
  const float* Whh1 = (const float*)d_in[2];
  const float* bih1 = (const float*)d_in[3];
  const float* bhh1 = (const float*)d_in[4];
  const float* Wih2 = (const float*)d_in[5];
  const float* Whh2 = (const float*)d_in[6];
  const float* bih2 = (const float*)d_in[7];
  const float* bhh2 = (const float*)d_in[8];
  const float* Wlin = (const float*)d_in[9];
  const float* blin = (const float*)d_in[10];
  float* outp = (float*)d_out;
  char* ws = (char*)d_ws;

  init_ws_kernel<<<dim3(128), dim3(256), 0, stream>>>(ws);

  (void)hipFuncSetAttribute((const void*)lstm_coop,
                            hipFuncAttributeMaxDynamicSharedMemorySize, LDS_TOTAL);

  void* args[] = { (void*)&xg, (void*)&Wih1, (void*)&Whh1, (void*)&bih1, (void*)&bhh1,
                   (void*)&Wih2, (void*)&Whh2, (void*)&bih2, (void*)&bhh2,
                   (void*)&Wlin, (void*)&blin, (void*)&outp, (void*)&ws };
  hipError_t err = hipLaunchCooperativeKernel((const void*)lstm_coop,
                                              dim3(NB), dim3(WGS), args, LDS_TOTAL, stream);
  if (err != hipSuccess) {
    lstm_coop<<<dim3(NB), dim3(WGS), LDS_TOTAL, stream>>>(
        xg, Wih1, Whh1, bih1, bhh1, Wih2, Whh2, bih2, bhh2, Wlin, blin, outp, ws);
  }
}

// Round 10
// 5852.130 us; speedup vs baseline: 1.1971x; 1.1971x over previous
//
#include <hip/hip_runtime.h>

// ============================================================================
// 2-layer LSTM (H=1024, B=128, T=256, future=64), persistent cooperative
// kernel, 256 WGs x 512 thr, 1 WG/CU, weights in LDS (MFMA B-frag order).
// R10: 16B-fragment layout. H planes stored [k>>3][row][8] f16 so each lane's
// MFMA A-fragment is ONE global_load_dwordx4 (no shuffles) -> VMEM instr
// count halves, bytes-in-flight double, stream goes latency-bound -> BW-bound.
// Writes: per-CU 8B sub-chunks (2 dwordx2/lane, sc0 sc1 write-through; only
// 2 CUs share a 16B row-chunk; L3 byte-enables, no RMW). Keeps R9's validated
// E1(t+1) hoist (arrivals at step end), atomic-reduce out path (no accO tile),
// and the XCD-leader single-fence rendezvous. NO register prefetch (R9's
// regression: VGPR 120, MfmaUtil halved).
// ============================================================================

typedef _Float16 f16;
typedef _Float16 f16x8 __attribute__((ext_vector_type(8)));
typedef float    f32x4 __attribute__((ext_vector_type(4)));
typedef int      i32x2 __attribute__((ext_vector_type(2)));
typedef int      i32x4 __attribute__((ext_vector_type(4)));
typedef unsigned int   u32;

#define NB   256
#define WGS  512
#define HS   1024
#define BS   128
#define TS   256
#define TTS  320
#define KST  32      // 1024 / 32
#define PSTR 131072  // f16 per plane: 128*128*8 (kgrp=128, row=128, 8)
#define NT   3       // weight tiles: G1(Whh1), G2a(Wih2), G2b(Whh2)

// workspace byte offsets
#define OFF_H1    0u         // f16 [2][128][128][8]        524288 B
#define OFF_H2    524288u    // f16 [2][128][128][8]        524288 B
#define OFF_CNT1  1048576u   // int [64 slots x 1024-int]   262144 B
#define OFF_CNT2  1310720u   // int [64 slots x 1024-int]   262144 B
#define OFF_FLAG  1572864u   // int [8 xcd x 2048-int]       65536 B
#define OFF_XREG  1638400u   // int [8 xcd x 16]               512 B
#define OFF_ACC   1638912u   // float [320][128]            163840 B
#define WS_END    1802752u

#define NSLOT       64
#define SLOT_TGT    4        // 256 blocks / 64 slots
#define SLOT_STRIDE 1024     // ints: 4KB between slots

// LDS byte offsets
#define LDS_G1    98304      // float[128][16]
#define LDS_G2    106496     // float[128][16]
#define LDS_XF    114688     // float[128]
#define LDS_PRM   115200     // wih1[16], b1[16], b2[16], blin
#define LDS_MISC  115456     // int[2]: xcd, leader
#define LDS_SH1   115584     // f16[512] stage h1 [row][4]
#define LDS_SH2   116608     // f16[512] stage h2 [row][4]
#define LDS_TOTAL 117760

__device__ __forceinline__ float sigm(float x){ return 1.0f/(1.0f + __expf(-x)); }

__device__ __forceinline__ void wt_store(u32* p, u32 v) {
  __hip_atomic_store(p, v, __ATOMIC_RELAXED, __HIP_MEMORY_SCOPE_AGENT);
}

// write-through 8B store (to coherence point; L3 byte-enables)
__device__ __forceinline__ void st8_wt(f16* addr, i32x2 d) {
  asm volatile("global_store_dwordx2 %0, %1, off sc0 sc1"
               :: "v"(addr), "v"(d) : "memory");
}

// per-lane slot poll (call from wv7: lane l polls slot l)
__device__ __forceinline__ void poll_slots(const int* cnt, int t) {
  const int* p = cnt + (threadIdx.x & 63) * SLOT_STRIDE + t;
  while (__hip_atomic_load(p, __ATOMIC_RELAXED, __HIP_MEMORY_SCOPE_AGENT) < SLOT_TGT)
    __builtin_amdgcn_s_sleep(1);
}

__global__ void init_ws_kernel(char* ws){
  // zero cnt1 + cnt2 + flags + xreg + accs (contiguous)
  const size_t n = (WS_END - OFF_CNT1) / 16u;
  float4* r = (float4*)(ws + OFF_CNT1);
  float4 z = make_float4(0.f, 0.f, 0.f, 0.f);
  size_t stride = (size_t)gridDim.x * blockDim.x;
  for (size_t i = blockIdx.x*(size_t)blockDim.x + threadIdx.x; i < n; i += stride) r[i] = z;
  __builtin_amdgcn_fence(__ATOMIC_RELEASE, "agent");
}

__global__ void __launch_bounds__(WGS, 2)
lstm_coop(const float* __restrict__ xg,
          const float* __restrict__ Wih1, const float* __restrict__ Whh1,
          const float* __restrict__ bih1, const float* __restrict__ bhh1,
          const float* __restrict__ Wih2, const float* __restrict__ Whh2,
          const float* __restrict__ bih2, const float* __restrict__ bhh2,
          const float* __restrict__ Wlin, const float* __restrict__ blin,
          float* __restrict__ outp, char* __restrict__ ws)
{
  extern __shared__ char smem[];
  f16*   Wlds = (f16*)smem;                    // [(tile*32+k0)*64+lane]*8 f16
  float* g1s  = (float*)(smem + LDS_G1);
  float* g2s  = (float*)(smem + LDS_G2);
  float* xfd  = (float*)(smem + LDS_XF);
  float* prm  = (float*)(smem + LDS_PRM);
  int*   miscl= (int*)(smem + LDS_MISC);
  f16*   sh1  = (f16*)(smem + LDS_SH1);
  f16*   sh2  = (f16*)(smem + LDS_SH2);

  f16* H1  = (f16*)(ws + OFF_H1);
  f16* H2  = (f16*)(ws + OFF_H2);
  int* cnt1 = (int*)(ws + OFF_CNT1);
  int* cnt2 = (int*)(ws + OFF_CNT2);
  int* flags= (int*)(ws + OFF_FLAG);
  float* accs = (float*)(ws + OFF_ACC);

  const int tid = threadIdx.x;
  const int blk = blockIdx.x;

  // ---- XCD self-id + leader election (rank0 of each XCC_ID group) ----
  int xcd_raw;
  asm("s_getreg_b32 %0, hwreg(HW_REG_XCC_ID)" : "=s"(xcd_raw));
  if (tid == 0) {
    int x = xcd_raw & 7;
    int rank = __hip_atomic_fetch_add((int*)(ws + OFF_XREG) + x*16, 1,
                                      __ATOMIC_RELAXED, __HIP_MEMORY_SCOPE_AGENT);
    miscl[0] = x;
    miscl[1] = (rank == 0) ? 1 : 0;
  }

  // ---- prologue: pack weights into LDS in MFMA B-frag order (3 tiles) ----
  for (int item = tid; item < NT*KST*64; item += WGS) {
    int tile = item >> 11;
    int rem  = item & 2047;
    int k0   = rem >> 6;
    int lane = rem & 63;
    int n    = lane & 15;
    int kbase = k0*32 + (lane>>4)*8;
    const float* Wsrc = (tile==0) ? Whh1 : (tile==1) ? Wih2 : Whh2;
    const float* p = Wsrc + (size_t)((n>>2)*1024 + blk*4 + (n&3))*HS + kbase;
    f16x8 pk;
    #pragma unroll
    for (int j=0;j<8;j++) pk[j] = (f16)p[j];
    *(f16x8*)(Wlds + (size_t)item*8) = pk;
  }
  if (tid < 16) {
    int row = (tid>>2)*1024 + blk*4 + (tid&3);
    prm[tid]      = Wih1[row];
    prm[16 + tid] = bih1[row] + bhh1[row];
    prm[32 + tid] = bih2[row] + bhh2[row];
  }
  if (tid == 16) prm[48] = blin[0];

  const int erow = tid >> 2;        // elementwise: batch row
  const int eu   = tid & 3;         // unit within CU
  const float wlin_c = Wlin[blk*4 + eu];
  float c1 = 0.f, c2 = 0.f;
  __syncthreads();

  const int  myxcd  = miscl[0];
  const bool leader = miscl[1] != 0;
  int* flag = flags + myxcd * 2048;         // monotone t+1

  // MFMA identity
  const int wv    = tid >> 6;
  const int lane  = tid & 63;
  const int n15   = lane & 15;
  const int mrow  = wv*16 + n15;          // A-frag row (batch)
  const int rbase = wv*16 + (lane>>4)*4;  // C/D row base
  const f16x8* WB = (const f16x8*)Wlds;
  // A-frag: elem(row,k) at (k>>3)*1024 + row*8 + (k&7); lane reads
  // k = k0*32 + (lane>>4)*8 + j  ->  ONE 16B load at:
  const int abase = (lane>>4)*1024 + mrow*8;   // + k0*4096 per k-step

  // h-write base: unit u=blk*4+eu -> (blk>>1)*1024 + row*8 + (blk&1)*4
  const int wbase = (blk>>1)*1024 + (blk&1)*4;

  // ---- prologue E1(0): h1(0) from x(0) only; store plane 0; arrive ----
  {
    float xv = xg[erow*TS + 0];
    float gi = xv*prm[0*4+eu] + prm[16 + 0*4+eu];
    float gg = xv*prm[2*4+eu] + prm[16 + 2*4+eu];
    float go = xv*prm[3*4+eu] + prm[16 + 3*4+eu];
    c1 = sigm(gi)*tanhf(gg);
    float h1v = sigm(go)*tanhf(c1);
    sh1[tid] = (f16)h1v;
  }
  __syncthreads();
  if (wv == 0) {
    st8_wt(H1 + (size_t)0*PSTR + wbase + lane*8,      *(const i32x2*)(sh1 + lane*4));
    st8_wt(H1 + (size_t)0*PSTR + wbase + (lane+64)*8, *(const i32x2*)(sh1 + (lane+64)*4));
    asm volatile("s_waitcnt vmcnt(0)" ::: "memory");
    if (lane == 0)
      __hip_atomic_fetch_add(cnt1 + (blk & (NSLOT-1))*SLOT_STRIDE + 0, 1,
                             __ATOMIC_RELAXED, __HIP_MEMORY_SCOPE_AGENT);
  }

  for (int t = 0; t < TTS; ++t) {
    const int p1 = t & 1;          // h1(t)/h2(t) plane (this step)
    const int p2 = (t + 1) & 1;    // h2(t-1) plane (read) == h1(t+1) plane

    // ---- [AR pre-phase] (t>=TS): E1(t) needs global out(t-1) ----
    if (t >= TS) {
      if (wv == 7) poll_slots(cnt2, t);
      __syncthreads();
      if (tid < BS)
        xfd[tid] = __hip_atomic_load(accs + (size_t)(t-1)*BS + tid,
                                     __ATOMIC_RELAXED, __HIP_MEMORY_SCOPE_AGENT) + prm[48];
      __syncthreads();
      {
        float xv = xfd[erow];
        float gi = g1s[erow*16 + 0*4+eu] + xv*prm[0*4+eu];
        float gf = g1s[erow*16 + 1*4+eu] + xv*prm[1*4+eu];
        float gg = g1s[erow*16 + 2*4+eu] + xv*prm[2*4+eu];
        float go = g1s[erow*16 + 3*4+eu] + xv*prm[3*4+eu];
        c1 = sigm(gf)*c1 + sigm(gi)*tanhf(gg);
        float h1v = sigm(go)*tanhf(c1);
        sh1[tid] = (f16)h1v;
      }
      __syncthreads();
      if (wv == 0) {
        st8_wt(H1 + (size_t)p1*PSTR + wbase + lane*8,      *(const i32x2*)(sh1 + lane*4));
        st8_wt(H1 + (size_t)p1*PSTR + wbase + (lane+64)*8, *(const i32x2*)(sh1 + (lane+64)*4));
        asm volatile("s_waitcnt vmcnt(0)" ::: "memory");
        if (lane == 0)
          __hip_atomic_fetch_add(cnt1 + (blk & (NSLOT-1))*SLOT_STRIDE + t, 1,
                                 __ATOMIC_RELAXED, __HIP_MEMORY_SCOPE_AGENT);
      }
    }

    // ---- [rendezvous] leader: poll both counters -> fence -> flag ----
    if (wv == 7) {
      if (leader) {
        if (t >= 1) poll_slots(cnt2, t);
        poll_slots(cnt1, t);
        __builtin_amdgcn_fence(__ATOMIC_ACQUIRE, "agent");   // one L1+L2 inv
        asm volatile("s_waitcnt vmcnt(0)" ::: "memory");
        if (lane == 0)
          __hip_atomic_store(flag, t + 1, __ATOMIC_RELAXED, __HIP_MEMORY_SCOPE_AGENT);
      } else {
        if (lane == 0) {
          while (__hip_atomic_load(flag, __ATOMIC_RELAXED, __HIP_MEMORY_SCOPE_AGENT) < t + 1)
            __builtin_amdgcn_s_sleep(1);
        }
      }
    }
    __syncthreads();

    // ---- [outp writer] col t-1 (sums final since cnt2[t]) ----
    if (t >= 1 && blk == ((t-1) & 255) && tid < BS) {
      float v = __hip_atomic_load(accs + (size_t)(t-1)*BS + tid,
                                  __ATOMIC_RELAXED, __HIP_MEMORY_SCOPE_AGENT) + prm[48];
      wt_store((u32*)&outp[tid*TTS + (t-1)], __builtin_bit_cast(u32, v));
    }

    // hoist next-step x load (TF)
    float xv_next = 0.0f;
    if (t + 1 <= TS-1) xv_next = xg[erow*TS + (t+1)];

    // ---- [stream] fused k-loop: 2x 16B loads + 3 MFMAs per k0 ----
    const f16* A1 = H1 + (size_t)p1*PSTR + abase;
    const f16* A2 = H2 + (size_t)p2*PSTR + abase;
    f32x4 acc1  = {0.f,0.f,0.f,0.f};
    f32x4 acc2a = {0.f,0.f,0.f,0.f};
    f32x4 acc2b = {0.f,0.f,0.f,0.f};
    if (t == 0) {   // h2(-1) == 0: h1-only
      #pragma unroll 8
      for (int k0 = 0; k0 < KST; ++k0) {
        f16x8 a1 = *(const f16x8*)(A1 + k0*4096);
        f16x8 b0 = WB[(0*KST + k0)*64 + lane];
        f16x8 b1 = WB[(1*KST + k0)*64 + lane];
        acc1  = __builtin_amdgcn_mfma_f32_16x16x32_f16(a1, b0, acc1,  0,0,0);
        acc2a = __builtin_amdgcn_mfma_f32_16x16x32_f16(a1, b1, acc2a, 0,0,0);
      }
    } else {
      #pragma unroll 8
      for (int k0 = 0; k0 < KST; ++k0) {
        f16x8 a1 = *(const f16x8*)(A1 + k0*4096);
        f16x8 a2 = *(const f16x8*)(A2 + k0*4096);
        f16x8 b0 = WB[(0*KST + k0)*64 + lane];
        f16x8 b1 = WB[(1*KST + k0)*64 + lane];
        f16x8 b2 = WB[(2*KST + k0)*64 + lane];
        acc1  = __builtin_amdgcn_mfma_f32_16x16x32_f16(a1, b0, acc1,  0,0,0);
        acc2a = __builtin_amdgcn_mfma_f32_16x16x32_f16(a1, b1, acc2a, 0,0,0);
        acc2b = __builtin_amdgcn_mfma_f32_16x16x32_f16(a2, b2, acc2b, 0,0,0);
      }
    }
    #pragma unroll
    for (int r = 0; r < 4; ++r) {
      int grow = rbase + r;
      g1s[grow*16 + n15] = acc1[r]  + prm[16 + n15];
      g2s[grow*16 + n15] = acc2a[r] + acc2b[r] + prm[32 + n15];
    }
    __syncthreads();

    // ---- [E2(t)] c2, h2; stage; out(t) partial dot + atomic reduce ----
    {
      float gi = g2s[erow*16 + 0*4+eu];
      float gf = g2s[erow*16 + 1*4+eu];
      float gg = g2s[erow*16 + 2*4+eu];
      float go = g2s[erow*16 + 3*4+eu];
      c2 = sigm(gf)*c2 + sigm(gi)*tanhf(gg);
      float h2v = sigm(go)*tanhf(c2);
      sh2[tid] = (f16)h2v;
      float p = h2v * wlin_c;
      p += __shfl_xor(p, 1);
      p += __shfl_xor(p, 2);
      if (eu == 0)
        __hip_atomic_fetch_add(accs + (size_t)t*BS + erow, p,
                               __ATOMIC_RELAXED, __HIP_MEMORY_SCOPE_AGENT);
    }

    // ---- [E1(t+1) hoist] (TF only; AR handled by next step's pre-phase) ----
    if (t + 1 <= TS-1) {
      float xv = xv_next;
      float gi = g1s[erow*16 + 0*4+eu] + xv*prm[0*4+eu];
      float gf = g1s[erow*16 + 1*4+eu] + xv*prm[1*4+eu];
      float gg = g1s[erow*16 + 2*4+eu] + xv*prm[2*4+eu];
      float go = g1s[erow*16 + 3*4+eu] + xv*prm[3*4+eu];
      c1 = sigm(gf)*c1 + sigm(gi)*tanhf(gg);
      float h1v = sigm(go)*tanhf(c1);
      sh1[tid] = (f16)h1v;
    }

    // drain all waves' atomic adds (and stores) before arrivals
    asm volatile("s_waitcnt vmcnt(0)" ::: "memory");
    __syncthreads();

    // ---- [stores + arrivals] last acts of the step ----
    if (wv == 0 && t + 1 <= TS-1) {   // h1(t+1), plane p2
      st8_wt(H1 + (size_t)p2*PSTR + wbase + lane*8,      *(const i32x2*)(sh1 + lane*4));
      st8_wt(H1 + (size_t)p2*PSTR + wbase + (lane+64)*8, *(const i32x2*)(sh1 + (lane+64)*4));
      asm volatile("s_waitcnt vmcnt(0)" ::: "memory");
      if (lane == 0)
        __hip_atomic_fetch_add(cnt1 + (blk & (NSLOT-1))*SLOT_STRIDE + (t+1), 1,
                               __ATOMIC_RELAXED, __HIP_MEMORY_SCOPE_AGENT);
    }
    if (wv == 1) {                    // h2(t), plane p1
      st8_wt(H2 + (size_t)p1*PSTR + wbase + lane*8,      *(const i32x2*)(sh2 + lane*4));
      st8_wt(H2 + (size_t)p1*PSTR + wbase + (lane+64)*8, *(const i32x2*)(sh2 + (lane+64)*4));
      asm volatile("s_waitcnt vmcnt(0)" ::: "memory");
      if (lane == 0)
        __hip_atomic_fetch_add(cnt2 + (blk & (NSLOT-1))*SLOT_STRIDE + (t+1), 1,
                               __ATOMIC_RELAXED, __HIP_MEMORY_SCOPE_AGENT);
    }
  }

  // ---- epilogue: outp col TTS-1 (writer block 63 = (TTS-1)&255) ----
  if (blk == 63) {
    if (wv == 7) poll_slots(cnt2, TTS);
    __syncthreads();
    if (tid < BS) {
      float v = __hip_atomic_load(accs + (size_t)(TTS-1)*BS + tid,
                                  __ATOMIC_RELAXED, __HIP_MEMORY_SCOPE_AGENT) + prm[48];
      wt_store((u32*)&outp[tid*TTS + (TTS-1)], __builtin_bit_cast(u32, v));
    }
  }
}

extern "C" void kernel_launch(void* const* d_in, const int* in_sizes, int n_in,
                              void* d_out, int out_size, void* d_ws, size_t ws_size,
                              hipStream_t stream) {
  const float* xg   = (const float*)d_in[0];
  const float* Wih1 = (const float*)d_in[1];
  const float* Whh1 = (const float*)d_in[2];
  const float* bih1 = (const float*)d_in[3];
  const float* bhh1 = (const float*)d_in[4];
  const float* Wih2 = (const float*)d_in[5];
  const float* Whh2 = (const float*)d_in[6];
  const float* bih2 = (const float*)d_in[7];
  const float* bhh2 = (const float*)d_in[8];
  const float* Wlin = (const float*)d_in[9];
  const float* blin = (const float*)d_in[10];
  float* outp = (float*)d_out;
  char* ws = (char*)d_ws;

  init_ws_kernel<<<dim3(128), dim3(256), 0, stream>>>(ws);

  (void)hipFuncSetAttribute((const void*)lstm_coop,
                            hipFuncAttributeMaxDynamicSharedMemorySize, LDS_TOTAL);

  void* args[] = { (void*)&xg, (void*)&Wih1, (void*)&Whh1, (void*)&bih1, (void*)&bhh1,
                   (void*)&Wih2, (void*)&Whh2, (void*)&bih2, (void*)&bhh2,
                   (void*)&Wlin, (void*)&blin, (void*)&outp, (void*)&ws };
  hipError_t err = hipLaunchCooperativeKernel((const void*)lstm_coop,
                                              dim3(NB), dim3(WGS), args, LDS_TOTAL, stream);
  if (err != hipSuccess) {
    lstm_coop<<<dim3(NB), dim3(WGS), LDS_TOTAL, stream>>>(
        xg, Wih1, Whh1, bih1, bhh1, Wih2, Whh2, bih2, bhh2, Wlin, blin, outp, ws);
  }
}

// Round 11
// 4633.636 us; speedup vs baseline: 1.5119x; 1.2630x over previous
//
#include <hip/hip_runtime.h>

// ============================================================================
// 2-layer LSTM (H=1024, B=128, T=256, future=64), persistent cooperative
// kernel, 256 WGs x 512 thr, 1 WG/CU, weights in LDS (MFMA B-frag order).
// R11 = R8 (best: 4690us) + accO-removal done right:
//  - k-loop is 3 MFMAs + 3 LDS B-reads per k0 (tile3 deleted; -25% LDS traffic)
//  - out(t) = partial dot (regs) + TWO-LEVEL reduce: atomic add to per-XCD
//    slot accs8[xcd][t][row] (32 serialized adds/addr, not 256 - the R10
//    mistake), writer block sums the 8 slots after the next rendezvous; AR
//    steps self-sum into xfd in the proven pre-phase.
//  - H layout, stream loop, stores, and the XCD-leader single-fence
//    rendezvous are EXACTLY R8's (R10's 16B-fragment layout reverted: it
//    doubled WRITE_SIZE via cross-CU partial-line writes and regressed 25%).
// ============================================================================

typedef _Float16 f16;
typedef _Float16 f16x8 __attribute__((ext_vector_type(8)));
typedef _Float16 f16x4 __attribute__((ext_vector_type(4)));
typedef float    f32x4 __attribute__((ext_vector_type(4)));
typedef int      i32x4 __attribute__((ext_vector_type(4)));
typedef unsigned int   u32;

#define NB   256
#define WGS  512
#define HS   1024
#define BS   128
#define TS   256
#define TTS  320
#define KST  32      // 1024 / 32
#define PSTR 131072  // f16 per plane: 256*128*4 (H1 and H2)
#define NT   3       // weight tiles: G1(Whh1), G2a(Wih2), G2b(Whh2)

// workspace byte offsets
#define OFF_H1    0u         // f16 [2][256][128][4]        524288 B
#define OFF_H2    524288u    // f16 [2][256][128][4]        524288 B
#define OFF_CNT1  1048576u   // int [64 slots x 512-int]    131072 B
#define OFF_CNT2  1179648u   // int [64 slots x 512-int]    131072 B
#define OFF_FLAG  1310720u   // int [8 xcd x 2048-int]       65536 B
#define OFF_XREG  1376256u   // int [8 xcd x 16]               512 B
#define OFF_ACC8  1376768u   // float [8][320][128]        1310720 B
#define WS_END    2687488u

#define NSLOT       64
#define SLOT_TGT    4        // 256 blocks / 64 slots
#define SLOT_STRIDE 512      // ints: 2KB between slots (t index max 320)

// LDS byte offsets
#define LDS_G1    98304      // float[128][16]
#define LDS_G2    106496     // float[128][16]
#define LDS_XF    114688     // float[128]
#define LDS_PRM   115200     // wih1[16], b1[16], b2[16], blin
#define LDS_MISC  115456     // int[2]: xcd, leader
#define LDS_SH1   115584     // f16[512] stage h1 [row][4]
#define LDS_SH2   116608     // f16[512] stage h2 [row][4]
#define LDS_TOTAL 117760

__device__ __forceinline__ float sigm(float x){ return 1.0f/(1.0f + __expf(-x)); }

__device__ __forceinline__ void wt_store(u32* p, u32 v) {
  __hip_atomic_store(p, v, __ATOMIC_RELAXED, __HIP_MEMORY_SCOPE_AGENT);
}

// full-line write-through 16B store (to coherence point)
__device__ __forceinline__ void st16_wt(f16* addr, f16x8 v) {
  i32x4 d = __builtin_bit_cast(i32x4, v);
  asm volatile("global_store_dwordx4 %0, %1, off sc0 sc1"
               :: "v"(addr), "v"(d) : "memory");
}

// per-lane slot poll (call from wv7: lane l polls slot l)
__device__ __forceinline__ void poll_slots(const int* cnt, int t) {
  const int* p = cnt + (threadIdx.x & 63) * SLOT_STRIDE + t;
  while (__hip_atomic_load(p, __ATOMIC_RELAXED, __HIP_MEMORY_SCOPE_AGENT) < SLOT_TGT)
    __builtin_amdgcn_s_sleep(1);
}

__global__ void init_ws_kernel(char* ws){
  // zero cnt1 + cnt2 + flags + xreg + accs8 (contiguous)
  const size_t n = (WS_END - OFF_CNT1) / 16u;
  float4* r = (float4*)(ws + OFF_CNT1);
  float4 z = make_float4(0.f, 0.f, 0.f, 0.f);
  size_t stride = (size_t)gridDim.x * blockDim.x;
  for (size_t i = blockIdx.x*(size_t)blockDim.x + threadIdx.x; i < n; i += stride) r[i] = z;
  __builtin_amdgcn_fence(__ATOMIC_RELEASE, "agent");
}

__global__ void __launch_bounds__(WGS, 2)
lstm_coop(const float* __restrict__ xg,
          const float* __restrict__ Wih1, const float* __restrict__ Whh1,
          const float* __restrict__ bih1, const float* __restrict__ bhh1,
          const float* __restrict__ Wih2, const float* __restrict__ Whh2,
          const float* __restrict__ bih2, const float* __restrict__ bhh2,
          const float* __restrict__ Wlin, const float* __restrict__ blin,
          float* __restrict__ outp, char* __restrict__ ws)
{
  extern __shared__ char smem[];
  f16*   Wlds = (f16*)smem;                    // [(tile*32+k0)*64+lane]*8 f16
  float* g1s  = (float*)(smem + LDS_G1);
  float* g2s  = (float*)(smem + LDS_G2);
  float* xfd  = (float*)(smem + LDS_XF);
  float* prm  = (float*)(smem + LDS_PRM);
  int*   miscl= (int*)(smem + LDS_MISC);
  f16*   sh1  = (f16*)(smem + LDS_SH1);
  f16*   sh2  = (f16*)(smem + LDS_SH2);

  f16* H1  = (f16*)(ws + OFF_H1);
  f16* H2  = (f16*)(ws + OFF_H2);
  int* cnt1 = (int*)(ws + OFF_CNT1);
  int* cnt2 = (int*)(ws + OFF_CNT2);
  int* flags= (int*)(ws + OFF_FLAG);
  float* accs8 = (float*)(ws + OFF_ACC8);     // [8][320][128]

  const int tid = threadIdx.x;
  const int blk = blockIdx.x;

  // ---- XCD self-id + leader election (rank0 of each XCC_ID group) ----
  int xcd_raw;
  asm("s_getreg_b32 %0, hwreg(HW_REG_XCC_ID)" : "=s"(xcd_raw));
  if (tid == 0) {
    int x = xcd_raw & 7;
    int rank = __hip_atomic_fetch_add((int*)(ws + OFF_XREG) + x*16, 1,
                                      __ATOMIC_RELAXED, __HIP_MEMORY_SCOPE_AGENT);
    miscl[0] = x;
    miscl[1] = (rank == 0) ? 1 : 0;
  }

  // ---- prologue: pack weights into LDS in MFMA B-frag order (3 tiles) ----
  for (int item = tid; item < NT*KST*64; item += WGS) {
    int tile = item >> 11;
    int rem  = item & 2047;
    int k0   = rem >> 6;
    int lane = rem & 63;
    int n    = lane & 15;
    int kbase = k0*32 + (lane>>4)*8;
    const float* Wsrc = (tile==0) ? Whh1 : (tile==1) ? Wih2 : Whh2;
    const float* p = Wsrc + (size_t)((n>>2)*1024 + blk*4 + (n&3))*HS + kbase;
    f16x8 pk;
    #pragma unroll
    for (int j=0;j<8;j++) pk[j] = (f16)p[j];
    *(f16x8*)(Wlds + (size_t)item*8) = pk;
  }
  if (tid < 16) {
    int row = (tid>>2)*1024 + blk*4 + (tid&3);
    prm[tid]      = Wih1[row];
    prm[16 + tid] = bih1[row] + bhh1[row];
    prm[32 + tid] = bih2[row] + bhh2[row];
  }
  if (tid == 16) prm[48] = blin[0];

  const int erow = tid >> 2;        // elementwise: batch row
  const int eu   = tid & 3;         // unit within CU
  const float wlin_c = Wlin[blk*4 + eu];
  float c1 = 0.f, c2 = 0.f;
  __syncthreads();

  const int  myxcd  = miscl[0];
  const bool leader = miscl[1] != 0;
  int* flag = flags + myxcd * 2048;         // monotone t+1
  float* myacc = accs8 + (size_t)myxcd * TTS * BS;

  // MFMA identity
  const int wv    = tid >> 6;
  const int lane  = tid & 63;
  const int n15   = lane & 15;
  const int mrow  = wv*16 + n15;          // A-frag row (batch)
  const int kc    = (lane>>4)*8;          // A/B-frag k sub-offset
  const int rbase = wv*16 + (lane>>4)*4;  // C/D row base
  const f16x8* WB = (const f16x8*)Wlds;
  const int abase = mrow*4 + (kc>>2)*512; // frag base (f16), H1 and H2

  for (int t = 0; t < TTS; ++t) {
    const int p1 = t & 1;          // h1(t)/h2(t) plane (this step)
    const int p2 = (t + 1) & 1;    // h2(t-1) plane (read this step)

    // ---- [AR pre-phase] (t>=TS): x(t) = out(t-1) = sum of 8 XCD slots ----
    if (t >= TS) {
      if (wv == 7) poll_slots(cnt2, t);
      __syncthreads();
      if (tid < BS) {
        float s = 0.f;
        #pragma unroll
        for (int x = 0; x < 8; ++x)
          s += __hip_atomic_load(accs8 + ((size_t)x*TTS + (t-1))*BS + tid,
                                 __ATOMIC_RELAXED, __HIP_MEMORY_SCOPE_AGENT);
        xfd[tid] = s + prm[48];
      }
      __syncthreads();
    }

    // ---- [E1(t)] block-local: g1s(t-1) + x(t) (or xfd) ----
    {
      float h1v;
      if (t == 0) {
        float xv = xg[erow*TS + 0];
        float gi = xv*prm[0*4+eu] + prm[16 + 0*4+eu];
        float gg = xv*prm[2*4+eu] + prm[16 + 2*4+eu];
        float go = xv*prm[3*4+eu] + prm[16 + 3*4+eu];
        c1 = sigm(gi)*tanhf(gg);
        h1v = sigm(go)*tanhf(c1);
      } else {
        float xv = (t < TS) ? xg[erow*TS + t] : xfd[erow];
        float gi = g1s[erow*16 + 0*4+eu] + xv*prm[0*4+eu];
        float gf = g1s[erow*16 + 1*4+eu] + xv*prm[1*4+eu];
        float gg = g1s[erow*16 + 2*4+eu] + xv*prm[2*4+eu];
        float go = g1s[erow*16 + 3*4+eu] + xv*prm[3*4+eu];
        c1 = sigm(gf)*c1 + sigm(gi)*tanhf(gg);
        h1v = sigm(go)*tanhf(c1);
      }
      sh1[tid] = (f16)h1v;
    }
    __syncthreads();

    // ---- [wv0] store h1(t) + arrive1 (wave-local ack) ----
    if (wv == 0) {
      st16_wt(H1 + (size_t)p1*PSTR + blk*512 + lane*8, *(const f16x8*)(sh1 + lane*8));
      asm volatile("s_waitcnt vmcnt(0)" ::: "memory");
      if (lane == 0)
        __hip_atomic_fetch_add(cnt1 + (blk & (NSLOT-1))*SLOT_STRIDE + t, 1,
                               __ATOMIC_RELAXED, __HIP_MEMORY_SCOPE_AGENT);
    }

    // ---- [rendezvous] leader: poll both counters -> fence -> flag ----
    if (wv == 7) {
      if (leader) {
        if (t >= 1) poll_slots(cnt2, t);
        poll_slots(cnt1, t);
        __builtin_amdgcn_fence(__ATOMIC_ACQUIRE, "agent");   // one L1+L2 inv
        asm volatile("s_waitcnt vmcnt(0)" ::: "memory");
        if (lane == 0)
          __hip_atomic_store(flag, t + 1, __ATOMIC_RELAXED, __HIP_MEMORY_SCOPE_AGENT);
      } else {
        if (lane == 0) {
          while (__hip_atomic_load(flag, __ATOMIC_RELAXED, __HIP_MEMORY_SCOPE_AGENT) < t + 1)
            __builtin_amdgcn_s_sleep(1);
        }
      }
    }
    __syncthreads();

    // ---- [outp writer] col t-1: rotating block sums the 8 XCD slots ----
    if (t >= 1 && blk == ((t-1) & 255) && tid < BS) {
      float v;
      if (t >= TS) {
        v = xfd[tid];
      } else {
        float s = 0.f;
        #pragma unroll
        for (int x = 0; x < 8; ++x)
          s += __hip_atomic_load(accs8 + ((size_t)x*TTS + (t-1))*BS + tid,
                                 __ATOMIC_RELAXED, __HIP_MEMORY_SCOPE_AGENT);
        v = s + prm[48];
      }
      wt_store((u32*)&outp[tid*TTS + (t-1)], __builtin_bit_cast(u32, v));
    }

    // ---- [stream] fused k-loop: 4x 8B loads + 3 B-frags + 3 MFMAs per k0 --
    const f16* A1 = H1 + (size_t)p1*PSTR + abase;
    const f16* A2 = H2 + (size_t)p2*PSTR + abase;
    f32x4 acc1  = {0.f,0.f,0.f,0.f};
    f32x4 acc2a = {0.f,0.f,0.f,0.f};
    f32x4 acc2b = {0.f,0.f,0.f,0.f};
    if (t == 0) {   // h2(-1) == 0: h1-only
      #pragma unroll 8
      for (int k0 = 0; k0 < KST; ++k0) {
        f16x4 a1l = *(const f16x4*)(A1 + k0*4096);
        f16x4 a1h = *(const f16x4*)(A1 + k0*4096 + 512);
        f16x8 a1  = __builtin_shufflevector(a1l, a1h, 0,1,2,3,4,5,6,7);
        f16x8 b0 = WB[(0*KST + k0)*64 + lane];
        f16x8 b1 = WB[(1*KST + k0)*64 + lane];
        acc1  = __builtin_amdgcn_mfma_f32_16x16x32_f16(a1, b0, acc1,  0,0,0);
        acc2a = __builtin_amdgcn_mfma_f32_16x16x32_f16(a1, b1, acc2a, 0,0,0);
      }
    } else {
      #pragma unroll 8
      for (int k0 = 0; k0 < KST; ++k0) {
        f16x4 a1l = *(const f16x4*)(A1 + k0*4096);
        f16x4 a1h = *(const f16x4*)(A1 + k0*4096 + 512);
        f16x4 a2l = *(const f16x4*)(A2 + k0*4096);
        f16x4 a2h = *(const f16x4*)(A2 + k0*4096 + 512);
        f16x8 a1  = __builtin_shufflevector(a1l, a1h, 0,1,2,3,4,5,6,7);
        f16x8 a2  = __builtin_shufflevector(a2l, a2h, 0,1,2,3,4,5,6,7);
        f16x8 b0 = WB[(0*KST + k0)*64 + lane];
        f16x8 b1 = WB[(1*KST + k0)*64 + lane];
        f16x8 b2 = WB[(2*KST + k0)*64 + lane];
        acc1  = __builtin_amdgcn_mfma_f32_16x16x32_f16(a1, b0, acc1,  0,0,0);
        acc2a = __builtin_amdgcn_mfma_f32_16x16x32_f16(a1, b1, acc2a, 0,0,0);
        acc2b = __builtin_amdgcn_mfma_f32_16x16x32_f16(a2, b2, acc2b, 0,0,0);
      }
    }
    #pragma unroll
    for (int r = 0; r < 4; ++r) {
      int grow = rbase + r;
      g1s[grow*16 + n15] = acc1[r]  + prm[16 + n15];
      g2s[grow*16 + n15] = acc2a[r] + acc2b[r] + prm[32 + n15];
    }
    __syncthreads();

    // ---- [E2(t)] c2, h2; stage; out(t) partial dot -> per-XCD atomic ----
    {
      float gi = g2s[erow*16 + 0*4+eu];
      float gf = g2s[erow*16 + 1*4+eu];
      float gg = g2s[erow*16 + 2*4+eu];
      float go = g2s[erow*16 + 3*4+eu];
      c2 = sigm(gf)*c2 + sigm(gi)*tanhf(gg);
      float h2v = sigm(go)*tanhf(c2);
      sh2[tid] = (f16)h2v;
      float p = h2v * wlin_c;
      p += __shfl_xor(p, 1);
      p += __shfl_xor(p, 2);
      if (eu == 0)
        __hip_atomic_fetch_add(myacc + (size_t)t*BS + erow, p,
                               __ATOMIC_RELAXED, __HIP_MEMORY_SCOPE_AGENT);
    }

    // drain all waves' atomic adds before the arrival that publishes them
    asm volatile("s_waitcnt vmcnt(0)" ::: "memory");
    __syncthreads();

    // ---- [wv1] store h2(t) + arrive2 (wave-local ack) ----
    if (wv == 1) {
      st16_wt(H2 + (size_t)p1*PSTR + blk*512 + lane*8, *(const f16x8*)(sh2 + lane*8));
      asm volatile("s_waitcnt vmcnt(0)" ::: "memory");
      if (lane == 0)
        __hip_atomic_fetch_add(cnt2 + (blk & (NSLOT-1))*SLOT_STRIDE + (t+1), 1,
                               __ATOMIC_RELAXED, __HIP_MEMORY_SCOPE_AGENT);
    }
  }

  // ---- epilogue: outp col TTS-1 (writer block 63 = (TTS-1)&255) ----
  if (blk == 63) {
    if (wv == 7) poll_slots(cnt2, TTS);
    __syncthreads();
    if (tid < BS) {
      float s = 0.f;
      #pragma unroll
      for (int x = 0; x < 8; ++x)
        s += __hip_atomic_load(accs8 + ((size_t)x*TTS + (TTS-1))*BS + tid,
                               __ATOMIC_RELAXED, __HIP_MEMORY_SCOPE_AGENT);
      wt_store((u32*)&outp[tid*TTS + (TTS-1)],
               __builtin_bit_cast(u32, s + prm[48]));
    }
  }
}

extern "C" void kernel_launch(void* const* d_in, const int* in_sizes, int n_in,
                              void* d_out, int out_size, void* d_ws, size_t ws_size,
                              hipStream_t stream) {
  const float* xg   = (const float*)d_in[0];
  const float* Wih1 = (const float*)d_in[1];
  const float* Whh1 = (const float*)d_in[2];
  const float* bih1 = (const float*)d_in[3];
  const float* bhh1 = (const float*)d_in[4];
  const float* Wih2 = (const float*)d_in[5];
  const float* Whh2 = (const float*)d_in[6];
  const float* bih2 = (const float*)d_in[7];
  const float* bhh2 = (const float*)d_in[8];
  const float* Wlin = (const float*)d_in[9];
  const float* blin = (const float*)d_in[10];
  float* outp = (float*)d_out;
  char* ws = (char*)d_ws;

  init_ws_kernel<<<dim3(128), dim3(256), 0, stream>>>(ws);

  (void)hipFuncSetAttribute((const void*)lstm_coop,
                            hipFuncAttributeMaxDynamicSharedMemorySize, LDS_TOTAL);

  void* args[] = { (void*)&xg, (void*)&Wih1, (void*)&Whh1, (void*)&bih1, (void*)&bhh1,
                   (void*)&Wih2, (void*)&Whh2, (void*)&bih2, (void*)&bhh2,
                   (void*)&Wlin, (void*)&blin, (void*)&outp, (void*)&ws };
  hipError_t err = hipLaunchCooperativeKernel((const void*)lstm_coop,
                                              dim3(NB), dim3(WGS), args, LDS_TOTAL, stream);
  if (err != hipSuccess) {
    lstm_coop<<<dim3(NB), dim3(WGS), LDS_TOTAL, stream>>>(
        xg, Wih1, Whh1, bih1, bhh1, Wih2, Whh2, bih2, bhh2, Wlin, blin, outp, ws);
  }
}

// Round 12
// 4515.973 us; speedup vs baseline: 1.5513x; 1.0261x over previous
//
#include <hip/hip_runtime.h>

// ============================================================================
// 2-layer LSTM (H=1024, B=128, T=256, future=64), persistent cooperative
// kernel, 256 WGs x 512 thr, 1 WG/CU, weights in LDS (MFMA B-frag order).
// R12 = R11 (best: 4634us) + two isolated changes:
//  1) E1-hoist (validated in R9): E1(t+1) computed at END of step t (TF), so
//     h1(t+1) store+arrive lands at step end next to h2(t)'s -> next step's
//     rendezvous finds both counters complete; exposed sync = fence+flag only.
//     AR steps keep the pre-phase (x(t)=out(t-1) needs the global reduce).
//  2) outp writer moved AFTER the arrivals (was pre-stream: made the rotating
//     writer block the per-step straggler).
// Everything else (stream loop, two-level out reduce, layout, rendezvous
// transport) is byte-identical to R11.
// ============================================================================

typedef _Float16 f16;
typedef _Float16 f16x8 __attribute__((ext_vector_type(8)));
typedef _Float16 f16x4 __attribute__((ext_vector_type(4)));
typedef float    f32x4 __attribute__((ext_vector_type(4)));
typedef int      i32x4 __attribute__((ext_vector_type(4)));
typedef unsigned int   u32;

#define NB   256
#define WGS  512
#define HS   1024
#define BS   128
#define TS   256
#define TTS  320
#define KST  32      // 1024 / 32
#define PSTR 131072  // f16 per plane: 256*128*4 (H1 and H2)
#define NT   3       // weight tiles: G1(Whh1), G2a(Wih2), G2b(Whh2)

// workspace byte offsets
#define OFF_H1    0u         // f16 [2][256][128][4]        524288 B
#define OFF_H2    524288u    // f16 [2][256][128][4]        524288 B
#define OFF_CNT1  1048576u   // int [64 slots x 512-int]    131072 B
#define OFF_CNT2  1179648u   // int [64 slots x 512-int]    131072 B
#define OFF_FLAG  1310720u   // int [8 xcd x 2048-int]       65536 B
#define OFF_XREG  1376256u   // int [8 xcd x 16]               512 B
#define OFF_ACC8  1376768u   // float [8][320][128]        1310720 B
#define WS_END    2687488u

#define NSLOT       64
#define SLOT_TGT    4        // 256 blocks / 64 slots
#define SLOT_STRIDE 512      // ints: 2KB between slots (t index max 320)

// LDS byte offsets
#define LDS_G1    98304      // float[128][16]
#define LDS_G2    106496     // float[128][16]
#define LDS_XF    114688     // float[128]
#define LDS_PRM   115200     // wih1[16], b1[16], b2[16], blin
#define LDS_MISC  115456     // int[2]: xcd, leader
#define LDS_SH1   115584     // f16[512] stage h1 [row][4]
#define LDS_SH2   116608     // f16[512] stage h2 [row][4]
#define LDS_TOTAL 117760

__device__ __forceinline__ float sigm(float x){ return 1.0f/(1.0f + __expf(-x)); }

__device__ __forceinline__ void wt_store(u32* p, u32 v) {
  __hip_atomic_store(p, v, __ATOMIC_RELAXED, __HIP_MEMORY_SCOPE_AGENT);
}

// full-line write-through 16B store (to coherence point)
__device__ __forceinline__ void st16_wt(f16* addr, f16x8 v) {
  i32x4 d = __builtin_bit_cast(i32x4, v);
  asm volatile("global_store_dwordx4 %0, %1, off sc0 sc1"
               :: "v"(addr), "v"(d) : "memory");
}

// per-lane slot poll (call from wv7: lane l polls slot l)
__device__ __forceinline__ void poll_slots(const int* cnt, int t) {
  const int* p = cnt + (threadIdx.x & 63) * SLOT_STRIDE + t;
  while (__hip_atomic_load(p, __ATOMIC_RELAXED, __HIP_MEMORY_SCOPE_AGENT) < SLOT_TGT)
    __builtin_amdgcn_s_sleep(1);
}

__global__ void init_ws_kernel(char* ws){
  // zero cnt1 + cnt2 + flags + xreg + accs8 (contiguous)
  const size_t n = (WS_END - OFF_CNT1) / 16u;
  float4* r = (float4*)(ws + OFF_CNT1);
  float4 z = make_float4(0.f, 0.f, 0.f, 0.f);
  size_t stride = (size_t)gridDim.x * blockDim.x;
  for (size_t i = blockIdx.x*(size_t)blockDim.x + threadIdx.x; i < n; i += stride) r[i] = z;
  __builtin_amdgcn_fence(__ATOMIC_RELEASE, "agent");
}

__global__ void __launch_bounds__(WGS, 2)
lstm_coop(const float* __restrict__ xg,
          const float* __restrict__ Wih1, const float* __restrict__ Whh1,
          const float* __restrict__ bih1, const float* __restrict__ bhh1,
          const float* __restrict__ Wih2, const float* __restrict__ Whh2,
          const float* __restrict__ bih2, const float* __restrict__ bhh2,
          const float* __restrict__ Wlin, const float* __restrict__ blin,
          float* __restrict__ outp, char* __restrict__ ws)
{
  extern __shared__ char smem[];
  f16*   Wlds = (f16*)smem;                    // [(tile*32+k0)*64+lane]*8 f16
  float* g1s  = (float*)(smem + LDS_G1);
  float* g2s  = (float*)(smem + LDS_G2);
  float* xfd  = (float*)(smem + LDS_XF);
  float* prm  = (float*)(smem + LDS_PRM);
  int*   miscl= (int*)(smem + LDS_MISC);
  f16*   sh1  = (f16*)(smem + LDS_SH1);
  f16*   sh2  = (f16*)(smem + LDS_SH2);

  f16* H1  = (f16*)(ws + OFF_H1);
  f16* H2  = (f16*)(ws + OFF_H2);
  int* cnt1 = (int*)(ws + OFF_CNT1);
  int* cnt2 = (int*)(ws + OFF_CNT2);
  int* flags= (int*)(ws + OFF_FLAG);
  float* accs8 = (float*)(ws + OFF_ACC8);     // [8][320][128]

  const int tid = threadIdx.x;
  const int blk = blockIdx.x;

  // ---- XCD self-id + leader election (rank0 of each XCC_ID group) ----
  int xcd_raw;
  asm("s_getreg_b32 %0, hwreg(HW_REG_XCC_ID)" : "=s"(xcd_raw));
  if (tid == 0) {
    int x = xcd_raw & 7;
    int rank = __hip_atomic_fetch_add((int*)(ws + OFF_XREG) + x*16, 1,
                                      __ATOMIC_RELAXED, __HIP_MEMORY_SCOPE_AGENT);
    miscl[0] = x;
    miscl[1] = (rank == 0) ? 1 : 0;
  }

  // ---- prologue: pack weights into LDS in MFMA B-frag order (3 tiles) ----
  for (int item = tid; item < NT*KST*64; item += WGS) {
    int tile = item >> 11;
    int rem  = item & 2047;
    int k0   = rem >> 6;
    int lane = rem & 63;
    int n    = lane & 15;
    int kbase = k0*32 + (lane>>4)*8;
    const float* Wsrc = (tile==0) ? Whh1 : (tile==1) ? Wih2 : Whh2;
    const float* p = Wsrc + (size_t)((n>>2)*1024 + blk*4 + (n&3))*HS + kbase;
    f16x8 pk;
    #pragma unroll
    for (int j=0;j<8;j++) pk[j] = (f16)p[j];
    *(f16x8*)(Wlds + (size_t)item*8) = pk;
  }
  if (tid < 16) {
    int row = (tid>>2)*1024 + blk*4 + (tid&3);
    prm[tid]      = Wih1[row];
    prm[16 + tid] = bih1[row] + bhh1[row];
    prm[32 + tid] = bih2[row] + bhh2[row];
  }
  if (tid == 16) prm[48] = blin[0];

  const int erow = tid >> 2;        // elementwise: batch row
  const int eu   = tid & 3;         // unit within CU
  const float wlin_c = Wlin[blk*4 + eu];
  float c1 = 0.f, c2 = 0.f;
  __syncthreads();

  const int  myxcd  = miscl[0];
  const bool leader = miscl[1] != 0;
  int* flag = flags + myxcd * 2048;         // monotone t+1
  float* myacc = accs8 + (size_t)myxcd * TTS * BS;

  // MFMA identity
  const int wv    = tid >> 6;
  const int lane  = tid & 63;
  const int n15   = lane & 15;
  const int mrow  = wv*16 + n15;          // A-frag row (batch)
  const int kc    = (lane>>4)*8;          // A/B-frag k sub-offset
  const int rbase = wv*16 + (lane>>4)*4;  // C/D row base
  const f16x8* WB = (const f16x8*)Wlds;
  const int abase = mrow*4 + (kc>>2)*512; // frag base (f16), H1 and H2

  // ---- prologue E1(0): h1(0) from x(0); store plane 0; arrive cnt1[0] ----
  {
    float xv = xg[erow*TS + 0];
    float gi = xv*prm[0*4+eu] + prm[16 + 0*4+eu];
    float gg = xv*prm[2*4+eu] + prm[16 + 2*4+eu];
    float go = xv*prm[3*4+eu] + prm[16 + 3*4+eu];
    c1 = sigm(gi)*tanhf(gg);
    float h1v = sigm(go)*tanhf(c1);
    sh1[tid] = (f16)h1v;
  }
  __syncthreads();
  if (wv == 0) {
    st16_wt(H1 + (size_t)0*PSTR + blk*512 + lane*8, *(const f16x8*)(sh1 + lane*8));
    asm volatile("s_waitcnt vmcnt(0)" ::: "memory");
    if (lane == 0)
      __hip_atomic_fetch_add(cnt1 + (blk & (NSLOT-1))*SLOT_STRIDE + 0, 1,
                             __ATOMIC_RELAXED, __HIP_MEMORY_SCOPE_AGENT);
  }

  for (int t = 0; t < TTS; ++t) {
    const int p1 = t & 1;          // h1(t)/h2(t) plane (this step)
    const int p2 = (t + 1) & 1;    // h2(t-1) plane (read) == h1(t+1) plane

    // ---- [AR pre-phase] (t>=TS): E1(t) needs out(t-1) = sum of 8 slots ----
    if (t >= TS) {
      if (wv == 7) poll_slots(cnt2, t);
      __syncthreads();
      if (tid < BS) {
        float s = 0.f;
        #pragma unroll
        for (int x = 0; x < 8; ++x)
          s += __hip_atomic_load(accs8 + ((size_t)x*TTS + (t-1))*BS + tid,
                                 __ATOMIC_RELAXED, __HIP_MEMORY_SCOPE_AGENT);
        xfd[tid] = s + prm[48];
      }
      __syncthreads();
      {
        float xv = xfd[erow];
        float gi = g1s[erow*16 + 0*4+eu] + xv*prm[0*4+eu];
        float gf = g1s[erow*16 + 1*4+eu] + xv*prm[1*4+eu];
        float gg = g1s[erow*16 + 2*4+eu] + xv*prm[2*4+eu];
        float go = g1s[erow*16 + 3*4+eu] + xv*prm[3*4+eu];
        c1 = sigm(gf)*c1 + sigm(gi)*tanhf(gg);
        float h1v = sigm(go)*tanhf(c1);
        sh1[tid] = (f16)h1v;
      }
      __syncthreads();
      if (wv == 0) {
        st16_wt(H1 + (size_t)p1*PSTR + blk*512 + lane*8, *(const f16x8*)(sh1 + lane*8));
        asm volatile("s_waitcnt vmcnt(0)" ::: "memory");
        if (lane == 0)
          __hip_atomic_fetch_add(cnt1 + (blk & (NSLOT-1))*SLOT_STRIDE + t, 1,
                                 __ATOMIC_RELAXED, __HIP_MEMORY_SCOPE_AGENT);
      }
    }

    // ---- [rendezvous] leader: poll both counters -> fence -> flag ----
    if (wv == 7) {
      if (leader) {
        if (t >= 1) poll_slots(cnt2, t);
        poll_slots(cnt1, t);
        __builtin_amdgcn_fence(__ATOMIC_ACQUIRE, "agent");   // one L1+L2 inv
        asm volatile("s_waitcnt vmcnt(0)" ::: "memory");
        if (lane == 0)
          __hip_atomic_store(flag, t + 1, __ATOMIC_RELAXED, __HIP_MEMORY_SCOPE_AGENT);
      } else {
        if (lane == 0) {
          while (__hip_atomic_load(flag, __ATOMIC_RELAXED, __HIP_MEMORY_SCOPE_AGENT) < t + 1)
            __builtin_amdgcn_s_sleep(1);
        }
      }
    }
    __syncthreads();

    // hoist next-step x load (TF)
    float xv_next = 0.0f;
    if (t + 1 <= TS-1) xv_next = xg[erow*TS + (t+1)];

    // ---- [stream] fused k-loop: 4x 8B loads + 3 B-frags + 3 MFMAs per k0 --
    const f16* A1 = H1 + (size_t)p1*PSTR + abase;
    const f16* A2 = H2 + (size_t)p2*PSTR + abase;
    f32x4 acc1  = {0.f,0.f,0.f,0.f};
    f32x4 acc2a = {0.f,0.f,0.f,0.f};
    f32x4 acc2b = {0.f,0.f,0.f,0.f};
    if (t == 0) {   // h2(-1) == 0: h1-only
      #pragma unroll 8
      for (int k0 = 0; k0 < KST; ++k0) {
        f16x4 a1l = *(const f16x4*)(A1 + k0*4096);
        f16x4 a1h = *(const f16x4*)(A1 + k0*4096 + 512);
        f16x8 a1  = __builtin_shufflevector(a1l, a1h, 0,1,2,3,4,5,6,7);
        f16x8 b0 = WB[(0*KST + k0)*64 + lane];
        f16x8 b1 = WB[(1*KST + k0)*64 + lane];
        acc1  = __builtin_amdgcn_mfma_f32_16x16x32_f16(a1, b0, acc1,  0,0,0);
        acc2a = __builtin_amdgcn_mfma_f32_16x16x32_f16(a1, b1, acc2a, 0,0,0);
      }
    } else {
      #pragma unroll 8
      for (int k0 = 0; k0 < KST; ++k0) {
        f16x4 a1l = *(const f16x4*)(A1 + k0*4096);
        f16x4 a1h = *(const f16x4*)(A1 + k0*4096 + 512);
        f16x4 a2l = *(const f16x4*)(A2 + k0*4096);
        f16x4 a2h = *(const f16x4*)(A2 + k0*4096 + 512);
        f16x8 a1  = __builtin_shufflevector(a1l, a1h, 0,1,2,3,4,5,6,7);
        f16x8 a2  = __builtin_shufflevector(a2l, a2h, 0,1,2,3,4,5,6,7);
        f16x8 b0 = WB[(0*KST + k0)*64 + lane];
        f16x8 b1 = WB[(1*KST + k0)*64 + lane];
        f16x8 b2 = WB[(2*KST + k0)*64 + lane];
        acc1  = __builtin_amdgcn_mfma_f32_16x16x32_f16(a1, b0, acc1,  0,0,0);
        acc2a = __builtin_amdgcn_mfma_f32_16x16x32_f16(a1, b1, acc2a, 0,0,0);
        acc2b = __builtin_amdgcn_mfma_f32_16x16x32_f16(a2, b2, acc2b, 0,0,0);
      }
    }
    #pragma unroll
    for (int r = 0; r < 4; ++r) {
      int grow = rbase + r;
      g1s[grow*16 + n15] = acc1[r]  + prm[16 + n15];
      g2s[grow*16 + n15] = acc2a[r] + acc2b[r] + prm[32 + n15];
    }
    __syncthreads();

    // ---- [E2(t)] c2, h2; stage; out(t) partial dot -> per-XCD atomic ----
    {
      float gi = g2s[erow*16 + 0*4+eu];
      float gf = g2s[erow*16 + 1*4+eu];
      float gg = g2s[erow*16 + 2*4+eu];
      float go = g2s[erow*16 + 3*4+eu];
      c2 = sigm(gf)*c2 + sigm(gi)*tanhf(gg);
      float h2v = sigm(go)*tanhf(c2);
      sh2[tid] = (f16)h2v;
      float p = h2v * wlin_c;
      p += __shfl_xor(p, 1);
      p += __shfl_xor(p, 2);
      if (eu == 0)
        __hip_atomic_fetch_add(myacc + (size_t)t*BS + erow, p,
                               __ATOMIC_RELAXED, __HIP_MEMORY_SCOPE_AGENT);
    }

    // ---- [E1(t+1) hoist] (TF only; AR handled by next step's pre-phase) ----
    if (t + 1 <= TS-1) {
      float xv = xv_next;
      float gi = g1s[erow*16 + 0*4+eu] + xv*prm[0*4+eu];
      float gf = g1s[erow*16 + 1*4+eu] + xv*prm[1*4+eu];
      float gg = g1s[erow*16 + 2*4+eu] + xv*prm[2*4+eu];
      float go = g1s[erow*16 + 3*4+eu] + xv*prm[3*4+eu];
      c1 = sigm(gf)*c1 + sigm(gi)*tanhf(gg);
      float h1v = sigm(go)*tanhf(c1);
      sh1[tid] = (f16)h1v;
    }

    // drain all waves' atomic adds before the arrivals that publish them
    asm volatile("s_waitcnt vmcnt(0)" ::: "memory");
    __syncthreads();

    // ---- [stores + arrivals] last acts of the step ----
    if (wv == 0 && t + 1 <= TS-1) {   // h1(t+1), plane p2
      st16_wt(H1 + (size_t)p2*PSTR + blk*512 + lane*8, *(const f16x8*)(sh1 + lane*8));
      asm volatile("s_waitcnt vmcnt(0)" ::: "memory");
      if (lane == 0)
        __hip_atomic_fetch_add(cnt1 + (blk & (NSLOT-1))*SLOT_STRIDE + (t+1), 1,
                               __ATOMIC_RELAXED, __HIP_MEMORY_SCOPE_AGENT);
    }
    if (wv == 1) {                    // h2(t), plane p1
      st16_wt(H2 + (size_t)p1*PSTR + blk*512 + lane*8, *(const f16x8*)(sh2 + lane*8));
      asm volatile("s_waitcnt vmcnt(0)" ::: "memory");
      if (lane == 0)
        __hip_atomic_fetch_add(cnt2 + (blk & (NSLOT-1))*SLOT_STRIDE + (t+1), 1,
                               __ATOMIC_RELAXED, __HIP_MEMORY_SCOPE_AGENT);
    }

    // ---- [outp writer] col t-1 (post-arrival; accs8[.][t-1] final since
    //      cnt2[t] was observed at this step's rendezvous) ----
    if (t >= 1 && blk == ((t-1) & 255) && tid < BS) {
      float v;
      if (t >= TS) {
        v = xfd[tid];   // out(t-1) computed in this step's pre-phase
      } else {
        float s = 0.f;
        #pragma unroll
        for (int x = 0; x < 8; ++x)
          s += __hip_atomic_load(accs8 + ((size_t)x*TTS + (t-1))*BS + tid,
                                 __ATOMIC_RELAXED, __HIP_MEMORY_SCOPE_AGENT);
        v = s + prm[48];
      }
      wt_store((u32*)&outp[tid*TTS + (t-1)], __builtin_bit_cast(u32, v));
    }
  }

  // ---- epilogue: outp col TTS-1 (writer block 63 = (TTS-1)&255) ----
  if (blk == 63) {
    if (wv == 7) poll_slots(cnt2, TTS);
    __syncthreads();
    if (tid < BS) {
      float s = 0.f;
      #pragma unroll
      for (int x = 0; x < 8; ++x)
        s += __hip_atomic_load(accs8 + ((size_t)x*TTS + (TTS-1))*BS + tid,
                               __ATOMIC_RELAXED, __HIP_MEMORY_SCOPE_AGENT);
      wt_store((u32*)&outp[tid*TTS + (TTS-1)],
               __builtin_bit_cast(u32, s + prm[48]));
    }
  }
}

extern "C" void kernel_launch(void* const* d_in, const int* in_sizes, int n_in,
                              void* d_out, int out_size, void* d_ws, size_t ws_size,
                              hipStream_t stream) {
  const float* xg   = (const float*)d_in[0];
  const float* Wih1 = (const float*)d_in[1];
  const float* Whh1 = (const float*)d_in[2];
  const float* bih1 = (const float*)d_in[3];
  const float* bhh1 = (const float*)d_in[4];
  const float* Wih2 = (const float*)d_in[5];
  const float* Whh2 = (const float*)d_in[6];
  const float* bih2 = (const float*)d_in[7];
  const float* bhh2 = (const float*)d_in[8];
  const float* Wlin = (const float*)d_in[9];
  const float* blin = (const float*)d_in[10];
  float* outp = (float*)d_out;
  char* ws = (char*)d_ws;

  init_ws_kernel<<<dim3(128), dim3(256), 0, stream>>>(ws);

  (void)hipFuncSetAttribute((const void*)lstm_coop,
                            hipFuncAttributeMaxDynamicSharedMemorySize, LDS_TOTAL);

  void* args[] = { (void*)&xg, (void*)&Wih1, (void*)&Whh1, (void*)&bih1, (void*)&bhh1,
                   (void*)&Wih2, (void*)&Whh2, (void*)&bih2, (void*)&bhh2,
                   (void*)&Wlin, (void*)&blin, (void*)&outp, (void*)&ws };
  hipError_t err = hipLaunchCooperativeKernel((const void*)lstm_coop,
                                              dim3(NB), dim3(WGS), args, LDS_TOTAL, stream);
  if (err != hipSuccess) {
    lstm_coop<<<dim3(NB), dim3(WGS), LDS_TOTAL, stream>>>(
        xg, Wih1, Whh1, bih1, bhh1, Wih2, Whh2, bih2, bhh2, Wlin, blin, outp, ws);
  }
}

// Round 13
// 4011.071 us; speedup vs baseline: 1.7465x; 1.1259x over previous
//
#include <hip/hip_runtime.h>

// ============================================================================
// 2-layer LSTM (H=1024, B=128, T=256, future=64), persistent cooperative
// kernel, 256 WGs x 1024 thr (16 waves), 1 WG/CU, weights in LDS.
// R13 = R12 (best: 4516us) + K-split 16-wave occupancy doubling:
//  - waves 0-7: k in [0,512); waves 8-15: k in [512,1024) for the same 8
//    row-tiles -> same instruction totals, 2x waves -> 2x memory-level
//    parallelism for the latency-exposed post-invalidate stream.
//  - upper half writes acc partials to LDS ([j][512] conflict-free, 16KB);
//    lower half adds partials into g1s/g2s (one extra __syncthreads).
//  - everything else (layout, two-level out reduce, E1-hoist, rendezvous,
//    stores/arrivals) identical to R12; elementwise guarded tid<512;
//    poller wave = wv15. __launch_bounds__(1024,4) keeps 16 waves resident.
// ============================================================================

typedef _Float16 f16;
typedef _Float16 f16x8 __attribute__((ext_vector_type(8)));
typedef _Float16 f16x4 __attribute__((ext_vector_type(4)));
typedef float    f32x4 __attribute__((ext_vector_type(4)));
typedef int      i32x4 __attribute__((ext_vector_type(4)));
typedef unsigned int   u32;

#define NB   256
#define WGS  1024
#define HS   1024
#define BS   128
#define TS   256
#define TTS  320
#define KST  32      // 1024 / 32
#define PSTR 131072  // f16 per plane: 256*128*4 (H1 and H2)
#define NT   3       // weight tiles: G1(Whh1), G2a(Wih2), G2b(Whh2)

// workspace byte offsets
#define OFF_H1    0u         // f16 [2][256][128][4]        524288 B
#define OFF_H2    524288u    // f16 [2][256][128][4]        524288 B
#define OFF_CNT1  1048576u   // int [64 slots x 512-int]    131072 B
#define OFF_CNT2  1179648u   // int [64 slots x 512-int]    131072 B
#define OFF_FLAG  1310720u   // int [8 xcd x 2048-int]       65536 B
#define OFF_XREG  1376256u   // int [8 xcd x 16]               512 B
#define OFF_ACC8  1376768u   // float [8][320][128]        1310720 B
#define WS_END    2687488u

#define NSLOT       64
#define SLOT_TGT    4        // 256 blocks / 64 slots
#define SLOT_STRIDE 512      // ints: 2KB between slots (t index max 320)

// LDS byte offsets
#define LDS_G1    98304      // float[128][16]
#define LDS_G2    106496     // float[128][16]
#define LDS_XF    114688     // float[128]
#define LDS_PRM   115200     // wih1[16], b1[16], b2[16], blin
#define LDS_MISC  115456     // int[2]: xcd, leader
#define LDS_SH1   115584     // f16[512] stage h1 [row][4]
#define LDS_SH2   116608     // f16[512] stage h2 [row][4]
#define LDS_PAC   117632     // float[8][512] partial accs (K-split reduce)
#define LDS_TOTAL 134016

__device__ __forceinline__ float sigm(float x){ return 1.0f/(1.0f + __expf(-x)); }

__device__ __forceinline__ void wt_store(u32* p, u32 v) {
  __hip_atomic_store(p, v, __ATOMIC_RELAXED, __HIP_MEMORY_SCOPE_AGENT);
}

// full-line write-through 16B store (to coherence point)
__device__ __forceinline__ void st16_wt(f16* addr, f16x8 v) {
  i32x4 d = __builtin_bit_cast(i32x4, v);
  asm volatile("global_store_dwordx4 %0, %1, off sc0 sc1"
               :: "v"(addr), "v"(d) : "memory");
}

// per-lane slot poll (call from poller wave: lane l polls slot l)
__device__ __forceinline__ void poll_slots(const int* cnt, int t) {
  const int* p = cnt + (threadIdx.x & 63) * SLOT_STRIDE + t;
  while (__hip_atomic_load(p, __ATOMIC_RELAXED, __HIP_MEMORY_SCOPE_AGENT) < SLOT_TGT)
    __builtin_amdgcn_s_sleep(1);
}

__global__ void init_ws_kernel(char* ws){
  // zero cnt1 + cnt2 + flags + xreg + accs8 (contiguous)
  const size_t n = (WS_END - OFF_CNT1) / 16u;
  float4* r = (float4*)(ws + OFF_CNT1);
  float4 z = make_float4(0.f, 0.f, 0.f, 0.f);
  size_t stride = (size_t)gridDim.x * blockDim.x;
  for (size_t i = blockIdx.x*(size_t)blockDim.x + threadIdx.x; i < n; i += stride) r[i] = z;
  __builtin_amdgcn_fence(__ATOMIC_RELEASE, "agent");
}

__global__ void __launch_bounds__(WGS, 4)
lstm_coop(const float* __restrict__ xg,
          const float* __restrict__ Wih1, const float* __restrict__ Whh1,
          const float* __restrict__ bih1, const float* __restrict__ bhh1,
          const float* __restrict__ Wih2, const float* __restrict__ Whh2,
          const float* __restrict__ bih2, const float* __restrict__ bhh2,
          const float* __restrict__ Wlin, const float* __restrict__ blin,
          float* __restrict__ outp, char* __restrict__ ws)
{
  extern __shared__ char smem[];
  f16*   Wlds = (f16*)smem;                    // [(tile*32+k0)*64+lane]*8 f16
  float* g1s  = (float*)(smem + LDS_G1);
  float* g2s  = (float*)(smem + LDS_G2);
  float* xfd  = (float*)(smem + LDS_XF);
  float* prm  = (float*)(smem + LDS_PRM);
  int*   miscl= (int*)(smem + LDS_MISC);
  f16*   sh1  = (f16*)(smem + LDS_SH1);
  f16*   sh2  = (f16*)(smem + LDS_SH2);
  float* pacc = (float*)(smem + LDS_PAC);      // [8][512]

  f16* H1  = (f16*)(ws + OFF_H1);
  f16* H2  = (f16*)(ws + OFF_H2);
  int* cnt1 = (int*)(ws + OFF_CNT1);
  int* cnt2 = (int*)(ws + OFF_CNT2);
  int* flags= (int*)(ws + OFF_FLAG);
  float* accs8 = (float*)(ws + OFF_ACC8);     // [8][320][128]

  const int tid = threadIdx.x;
  const int blk = blockIdx.x;

  // ---- XCD self-id + leader election (rank0 of each XCC_ID group) ----
  int xcd_raw;
  asm("s_getreg_b32 %0, hwreg(HW_REG_XCC_ID)" : "=s"(xcd_raw));
  if (tid == 0) {
    int x = xcd_raw & 7;
    int rank = __hip_atomic_fetch_add((int*)(ws + OFF_XREG) + x*16, 1,
                                      __ATOMIC_RELAXED, __HIP_MEMORY_SCOPE_AGENT);
    miscl[0] = x;
    miscl[1] = (rank == 0) ? 1 : 0;
  }

  // ---- prologue: pack weights into LDS in MFMA B-frag order (3 tiles) ----
  for (int item = tid; item < NT*KST*64; item += WGS) {
    int tile = item >> 11;
    int rem  = item & 2047;
    int k0   = rem >> 6;
    int lane = rem & 63;
    int n    = lane & 15;
    int kbase = k0*32 + (lane>>4)*8;
    const float* Wsrc = (tile==0) ? Whh1 : (tile==1) ? Wih2 : Whh2;
    const float* p = Wsrc + (size_t)((n>>2)*1024 + blk*4 + (n&3))*HS + kbase;
    f16x8 pk;
    #pragma unroll
    for (int j=0;j<8;j++) pk[j] = (f16)p[j];
    *(f16x8*)(Wlds + (size_t)item*8) = pk;
  }
  if (tid < 16) {
    int row = (tid>>2)*1024 + blk*4 + (tid&3);
    prm[tid]      = Wih1[row];
    prm[16 + tid] = bih1[row] + bhh1[row];
    prm[32 + tid] = bih2[row] + bhh2[row];
  }
  if (tid == 16) prm[48] = blin[0];

  const int erow = tid >> 2;        // elementwise: batch row (tid<512 only)
  const int eu   = tid & 3;         // unit within CU
  const float wlin_c = Wlin[blk*4 + eu];
  float c1 = 0.f, c2 = 0.f;
  __syncthreads();

  const int  myxcd  = miscl[0];
  const bool leader = miscl[1] != 0;
  int* flag = flags + myxcd * 2048;         // monotone t+1
  float* myacc = accs8 + (size_t)myxcd * TTS * BS;

  // MFMA identity (K-split)
  const int wv    = tid >> 6;
  const int lane  = tid & 63;
  const int half  = wv >> 3;              // 0: k[0,512), 1: k[512,1024)
  const int wl    = wv & 7;               // row-tile index
  const int n15   = lane & 15;
  const int mrow  = wl*16 + n15;          // A-frag row (batch)
  const int kc    = (lane>>4)*8;          // A/B-frag k sub-offset
  const int rbase = wl*16 + (lane>>4)*4;  // C/D row base
  const f16x8* WB = (const f16x8*)Wlds;
  const int abase = mrow*4 + (kc>>2)*512; // frag base (f16), H1 and H2
  const int k0beg = half*16;              // 16 k-steps per half

  // ---- prologue E1(0): h1(0) from x(0); store plane 0; arrive cnt1[0] ----
  if (tid < 512) {
    float xv = xg[erow*TS + 0];
    float gi = xv*prm[0*4+eu] + prm[16 + 0*4+eu];
    float gg = xv*prm[2*4+eu] + prm[16 + 2*4+eu];
    float go = xv*prm[3*4+eu] + prm[16 + 3*4+eu];
    c1 = sigm(gi)*tanhf(gg);
    float h1v = sigm(go)*tanhf(c1);
    sh1[tid] = (f16)h1v;
  }
  __syncthreads();
  if (wv == 0) {
    st16_wt(H1 + (size_t)0*PSTR + blk*512 + lane*8, *(const f16x8*)(sh1 + lane*8));
    asm volatile("s_waitcnt vmcnt(0)" ::: "memory");
    if (lane == 0)
      __hip_atomic_fetch_add(cnt1 + (blk & (NSLOT-1))*SLOT_STRIDE + 0, 1,
                             __ATOMIC_RELAXED, __HIP_MEMORY_SCOPE_AGENT);
  }

  for (int t = 0; t < TTS; ++t) {
    const int p1 = t & 1;          // h1(t)/h2(t) plane (this step)
    const int p2 = (t + 1) & 1;    // h2(t-1) plane (read) == h1(t+1) plane

    // ---- [AR pre-phase] (t>=TS): E1(t) needs out(t-1) = sum of 8 slots ----
    if (t >= TS) {
      if (wv == 15) poll_slots(cnt2, t);
      __syncthreads();
      if (tid < BS) {
        float s = 0.f;
        #pragma unroll
        for (int x = 0; x < 8; ++x)
          s += __hip_atomic_load(accs8 + ((size_t)x*TTS + (t-1))*BS + tid,
                                 __ATOMIC_RELAXED, __HIP_MEMORY_SCOPE_AGENT);
        xfd[tid] = s + prm[48];
      }
      __syncthreads();
      if (tid < 512) {
        float xv = xfd[erow];
        float gi = g1s[erow*16 + 0*4+eu] + xv*prm[0*4+eu];
        float gf = g1s[erow*16 + 1*4+eu] + xv*prm[1*4+eu];
        float gg = g1s[erow*16 + 2*4+eu] + xv*prm[2*4+eu];
        float go = g1s[erow*16 + 3*4+eu] + xv*prm[3*4+eu];
        c1 = sigm(gf)*c1 + sigm(gi)*tanhf(gg);
        float h1v = sigm(go)*tanhf(c1);
        sh1[tid] = (f16)h1v;
      }
      __syncthreads();
      if (wv == 0) {
        st16_wt(H1 + (size_t)p1*PSTR + blk*512 + lane*8, *(const f16x8*)(sh1 + lane*8));
        asm volatile("s_waitcnt vmcnt(0)" ::: "memory");
        if (lane == 0)
          __hip_atomic_fetch_add(cnt1 + (blk & (NSLOT-1))*SLOT_STRIDE + t, 1,
                                 __ATOMIC_RELAXED, __HIP_MEMORY_SCOPE_AGENT);
      }
    }

    // ---- [rendezvous] leader: poll both counters -> fence -> flag ----
    if (wv == 15) {
      if (leader) {
        if (t >= 1) poll_slots(cnt2, t);
        poll_slots(cnt1, t);
        __builtin_amdgcn_fence(__ATOMIC_ACQUIRE, "agent");   // one L1+L2 inv
        asm volatile("s_waitcnt vmcnt(0)" ::: "memory");
        if (lane == 0)
          __hip_atomic_store(flag, t + 1, __ATOMIC_RELAXED, __HIP_MEMORY_SCOPE_AGENT);
      } else {
        if (lane == 0) {
          while (__hip_atomic_load(flag, __ATOMIC_RELAXED, __HIP_MEMORY_SCOPE_AGENT) < t + 1)
            __builtin_amdgcn_s_sleep(1);
        }
      }
    }
    __syncthreads();

    // hoist next-step x load (TF)
    float xv_next = 0.0f;
    if (tid < 512 && t + 1 <= TS-1) xv_next = xg[erow*TS + (t+1)];

    // ---- [stream] K-split fused k-loop: each wave does its 16 k-steps ----
    const f16* A1 = H1 + (size_t)p1*PSTR + abase;
    const f16* A2 = H2 + (size_t)p2*PSTR + abase;
    f32x4 acc1  = {0.f,0.f,0.f,0.f};
    f32x4 acc2a = {0.f,0.f,0.f,0.f};
    f32x4 acc2b = {0.f,0.f,0.f,0.f};
    if (t == 0) {   // h2(-1) == 0: h1-only
      #pragma unroll 8
      for (int kk = 0; kk < 16; ++kk) {
        int k0 = k0beg + kk;
        f16x4 a1l = *(const f16x4*)(A1 + k0*4096);
        f16x4 a1h = *(const f16x4*)(A1 + k0*4096 + 512);
        f16x8 a1  = __builtin_shufflevector(a1l, a1h, 0,1,2,3,4,5,6,7);
        f16x8 b0 = WB[(0*KST + k0)*64 + lane];
        f16x8 b1 = WB[(1*KST + k0)*64 + lane];
        acc1  = __builtin_amdgcn_mfma_f32_16x16x32_f16(a1, b0, acc1,  0,0,0);
        acc2a = __builtin_amdgcn_mfma_f32_16x16x32_f16(a1, b1, acc2a, 0,0,0);
      }
    } else {
      #pragma unroll 8
      for (int kk = 0; kk < 16; ++kk) {
        int k0 = k0beg + kk;
        f16x4 a1l = *(const f16x4*)(A1 + k0*4096);
        f16x4 a1h = *(const f16x4*)(A1 + k0*4096 + 512);
        f16x4 a2l = *(const f16x4*)(A2 + k0*4096);
        f16x4 a2h = *(const f16x4*)(A2 + k0*4096 + 512);
        f16x8 a1  = __builtin_shufflevector(a1l, a1h, 0,1,2,3,4,5,6,7);
        f16x8 a2  = __builtin_shufflevector(a2l, a2h, 0,1,2,3,4,5,6,7);
        f16x8 b0 = WB[(0*KST + k0)*64 + lane];
        f16x8 b1 = WB[(1*KST + k0)*64 + lane];
        f16x8 b2 = WB[(2*KST + k0)*64 + lane];
        acc1  = __builtin_amdgcn_mfma_f32_16x16x32_f16(a1, b0, acc1,  0,0,0);
        acc2a = __builtin_amdgcn_mfma_f32_16x16x32_f16(a1, b1, acc2a, 0,0,0);
        acc2b = __builtin_amdgcn_mfma_f32_16x16x32_f16(a2, b2, acc2b, 0,0,0);
      }
    }
    // ---- K-split reduce: upper half deposits partials; lower half sums ----
    if (half == 1) {
      #pragma unroll
      for (int r = 0; r < 4; ++r) {
        pacc[r*512     + wl*64 + lane] = acc1[r];
        pacc[(4+r)*512 + wl*64 + lane] = acc2a[r] + acc2b[r];
      }
    }
    __syncthreads();
    if (half == 0) {
      #pragma unroll
      for (int r = 0; r < 4; ++r) {
        int grow = rbase + r;
        g1s[grow*16 + n15] = acc1[r] + pacc[r*512 + wl*64 + lane]
                             + prm[16 + n15];
        g2s[grow*16 + n15] = acc2a[r] + acc2b[r] + pacc[(4+r)*512 + wl*64 + lane]
                             + prm[32 + n15];
      }
    }
    __syncthreads();

    // ---- [E2(t)] c2, h2; stage; out(t) partial dot -> per-XCD atomic ----
    if (tid < 512) {
      float gi = g2s[erow*16 + 0*4+eu];
      float gf = g2s[erow*16 + 1*4+eu];
      float gg = g2s[erow*16 + 2*4+eu];
      float go = g2s[erow*16 + 3*4+eu];
      c2 = sigm(gf)*c2 + sigm(gi)*tanhf(gg);
      float h2v = sigm(go)*tanhf(c2);
      sh2[tid] = (f16)h2v;
      float p = h2v * wlin_c;
      p += __shfl_xor(p, 1);
      p += __shfl_xor(p, 2);
      if (eu == 0)
        __hip_atomic_fetch_add(myacc + (size_t)t*BS + erow, p,
                               __ATOMIC_RELAXED, __HIP_MEMORY_SCOPE_AGENT);
    }

    // ---- [E1(t+1) hoist] (TF only; AR handled by next step's pre-phase) ----
    if (tid < 512 && t + 1 <= TS-1) {
      float xv = xv_next;
      float gi = g1s[erow*16 + 0*4+eu] + xv*prm[0*4+eu];
      float gf = g1s[erow*16 + 1*4+eu] + xv*prm[1*4+eu];
      float gg = g1s[erow*16 + 2*4+eu] + xv*prm[2*4+eu];
      float go = g1s[erow*16 + 3*4+eu] + xv*prm[3*4+eu];
      c1 = sigm(gf)*c1 + sigm(gi)*tanhf(gg);
      float h1v = sigm(go)*tanhf(c1);
      sh1[tid] = (f16)h1v;
    }

    // drain all waves' atomic adds before the arrivals that publish them
    asm volatile("s_waitcnt vmcnt(0)" ::: "memory");
    __syncthreads();

    // ---- [stores + arrivals] last acts of the step ----
    if (wv == 0 && t + 1 <= TS-1) {   // h1(t+1), plane p2
      st16_wt(H1 + (size_t)p2*PSTR + blk*512 + lane*8, *(const f16x8*)(sh1 + lane*8));
      asm volatile("s_waitcnt vmcnt(0)" ::: "memory");
      if (lane == 0)
        __hip_atomic_fetch_add(cnt1 + (blk & (NSLOT-1))*SLOT_STRIDE + (t+1), 1,
                               __ATOMIC_RELAXED, __HIP_MEMORY_SCOPE_AGENT);
    }
    if (wv == 1) {                    // h2(t), plane p1
      st16_wt(H2 + (size_t)p1*PSTR + blk*512 + lane*8, *(const f16x8*)(sh2 + lane*8));
      asm volatile("s_waitcnt vmcnt(0)" ::: "memory");
      if (lane == 0)
        __hip_atomic_fetch_add(cnt2 + (blk & (NSLOT-1))*SLOT_STRIDE + (t+1), 1,
                               __ATOMIC_RELAXED, __HIP_MEMORY_SCOPE_AGENT);
    }

    // ---- [outp writer] col t-1 (post-arrival; accs8[.][t-1] final since
    //      cnt2[t] was observed at this step's rendezvous) ----
    if (t >= 1 && blk == ((t-1) & 255) && tid < BS) {
      float v;
      if (t >= TS) {
        v = xfd[tid];   // out(t-1) computed in this step's pre-phase
      } else {
        float s = 0.f;
        #pragma unroll
        for (int x = 0; x < 8; ++x)
          s += __hip_atomic_load(accs8 + ((size_t)x*TTS + (t-1))*BS + tid,
                                 __ATOMIC_RELAXED, __HIP_MEMORY_SCOPE_AGENT);
        v = s + prm[48];
      }
      wt_store((u32*)&outp[tid*TTS + (t-1)], __builtin_bit_cast(u32, v));
    }
  }

  // ---- epilogue: outp col TTS-1 (writer block 63 = (TTS-1)&255) ----
  if (blk == 63) {
    if (wv == 15) poll_slots(cnt2, TTS);
    __syncthreads();
    if (tid < BS) {
      float s = 0.f;
      #pragma unroll
      for (int x = 0; x < 8; ++x)
        s += __hip_atomic_load(accs8 + ((size_t)x*TTS + (TTS-1))*BS + tid,
                               __ATOMIC_RELAXED, __HIP_MEMORY_SCOPE_AGENT);
      wt_store((u32*)&outp[tid*TTS + (TTS-1)],
               __builtin_bit_cast(u32, s + prm[48]));
    }
  }
}

extern "C" void kernel_launch(void* const* d_in, const int* in_sizes, int n_in,
                              void* d_out, int out_size, void* d_ws, size_t ws_size,
                              hipStream_t stream) {
  const float* xg   = (const float*)d_in[0];
  const float* Wih1 = (const float*)d_in[1];
  const float* Whh1 = (const float*)d_in[2];
  const float* bih1 = (const float*)d_in[3];
  const float* bhh1 = (const float*)d_in[4];
  const float* Wih2 = (const float*)d_in[5];
  const float* Whh2 = (const float*)d_in[6];
  const float* bih2 = (const float*)d_in[7];
  const float* bhh2 = (const float*)d_in[8];
  const float* Wlin = (const float*)d_in[9];
  const float* blin = (const float*)d_in[10];
  float* outp = (float*)d_out;
  char* ws = (char*)d_ws;

  init_ws_kernel<<<dim3(128), dim3(256), 0, stream>>>(ws);

  (void)hipFuncSetAttribute((const void*)lstm_coop,
                            hipFuncAttributeMaxDynamicSharedMemorySize, LDS_TOTAL);

  void* args[] = { (void*)&xg, (void*)&Wih1, (void*)&Whh1, (void*)&bih1, (void*)&bhh1,
                   (void*)&Wih2, (void*)&Whh2, (void*)&bih2, (void*)&bhh2,
                   (void*)&Wlin, (void*)&blin, (void*)&outp, (void*)&ws };
  hipError_t err = hipLaunchCooperativeKernel((const void*)lstm_coop,
                                              dim3(NB), dim3(WGS), args, LDS_TOTAL, stream);
  if (err != hipSuccess) {
    lstm_coop<<<dim3(NB), dim3(WGS), LDS_TOTAL, stream>>>(
        xg, Wih1, Whh1, bih1, bhh1, Wih2, Whh2, bih2, bhh2, Wlin, blin, outp, ws);
  }
}